// Round 1
// baseline (1056.468 us; speedup 1.0000x reference)
//
#include <hip/hip_runtime.h>
#include <hip/hip_bf16.h>

#define BB 4
#define NN 32
#define MM 64
#define KK 16
#define KK1 17
#define PP 128
#define CC 2
#define AWD 64
#define TWD 256
#define WD 128

__device__ __forceinline__ float fast_tanh(float x) {
    // (e^{2x}-1)/(e^{2x}+1); exact formula, __expf ~1e-6 rel err, saturates correctly
    float e = __expf(2.0f * x);
    return 1.0f - 2.0f / (e + 1.0f);
}

// ---------------------------------------------------------------------------
// Kernel A: attention MLP + masked softmax over P + coeff = exp(-attn@sigma)
// one block per (b,n,k); 128 threads = one per p
// ---------------------------------------------------------------------------
__global__ __launch_bounds__(128) void attn_kernel(
    const float* __restrict__ phase,   // (B,N,4)
    const float* __restrict__ posc,    // (B,P,2)
    const float* __restrict__ sigma,   // (B,P,2)
    const float* __restrict__ velc,    // (B,K,2)
    const float* __restrict__ aw0, const float* __restrict__ ab0,
    const float* __restrict__ aw1, const float* __restrict__ ab1,
    const float* __restrict__ aw2, const float* __restrict__ ab2,
    float* __restrict__ coeff)         // (B,N,K1,2) workspace
{
    __shared__ __align__(16) float s_aw0[6 * AWD];     // [j][i] layout
    __shared__ __align__(16) float s_aw1t[AWD * AWD];  // transposed: [i][j]
    __shared__ float s_ab0[AWD];
    __shared__ float s_ab1[AWD];
    __shared__ float s_aw2[AWD];
    __shared__ float s_red[8];

    const int tid = threadIdx.x;
    const int blk = blockIdx.x;
    const int b = blk / (NN * KK1);
    const int rem = blk % (NN * KK1);
    const int n = rem / KK1;
    const int k = rem % KK1;

    for (int idx = tid; idx < 6 * AWD; idx += 128) s_aw0[idx] = aw0[idx];
    for (int idx = tid; idx < AWD * AWD; idx += 128) {
        int j = idx >> 6, i = idx & 63;
        s_aw1t[i * AWD + j] = aw1[idx];
    }
    if (tid < AWD) { s_ab0[tid] = ab0[tid]; s_ab1[tid] = ab1[tid]; s_aw2[tid] = aw2[tid]; }
    __syncthreads();

    const int p = tid;
    const float x0 = phase[(b * NN + n) * 4 + 0];
    const float x1 = phase[(b * NN + n) * 4 + 1];
    float va0, va1;
    if (k == 0) {
        va0 = phase[(b * NN + n) * 4 + 2];
        va1 = phase[(b * NN + n) * 4 + 3];
    } else {
        va0 = velc[(b * KK + (k - 1)) * 2 + 0];
        va1 = velc[(b * KK + (k - 1)) * 2 + 1];
    }
    const float inv = rsqrtf(va0 * va0 + va1 * va1 + 1e-16f);
    const float ag0 = va0 * inv, ag1 = va1 * inv;
    const float px = posc[(b * PP + p) * 2 + 0];
    const float py = posc[(b * PP + p) * 2 + 1];
    const float r0 = x0 - px, r1 = x1 - py;
    const float rd = sqrtf(r0 * r0 + r1 * r1 + 1e-16f);
    const float pl = r0 * ag0 + r1 * ag1;
    const float al = pl / (rd + 1e-8f);

    float f[6] = {x0, x1, va0, va1, al, pl};

    float h0[AWD];
    #pragma unroll 4
    for (int i = 0; i < AWD; ++i) {
        float a = s_ab0[i];
        #pragma unroll
        for (int j = 0; j < 6; ++j) a += f[j] * s_aw0[j * AWD + i];
        h0[i] = fast_tanh(a);
    }

    float logit = ab2[0];
    #pragma unroll 2
    for (int i = 0; i < AWD; ++i) {
        float a = s_ab1[i];
        const float4* w4 = (const float4*)&s_aw1t[i * AWD];
        #pragma unroll
        for (int j4 = 0; j4 < AWD / 4; ++j4) {
            float4 w = w4[j4];
            a += h0[4 * j4 + 0] * w.x + h0[4 * j4 + 1] * w.y +
                 h0[4 * j4 + 2] * w.z + h0[4 * j4 + 3] * w.w;
        }
        logit += fast_tanh(a) * s_aw2[i];
    }

    const float ml = (pl > 0.0f) ? logit : -1e30f;
    const int lane = tid & 63, wid = tid >> 6;

    // block max
    float mv = ml;
    for (int o = 32; o > 0; o >>= 1) mv = fmaxf(mv, __shfl_xor(mv, o, 64));
    if (lane == 0) s_red[wid] = mv;
    __syncthreads();
    mv = fmaxf(s_red[0], s_red[1]);

    const float ew = __expf(ml - mv);
    float sv = ew;
    for (int o = 32; o > 0; o >>= 1) sv += __shfl_xor(sv, o, 64);
    if (lane == 0) s_red[2 + wid] = sv;
    __syncthreads();
    sv = s_red[2] + s_red[3];
    const float attn = ew / sv;

    float s0 = attn * sigma[(b * PP + p) * 2 + 0];
    float s1 = attn * sigma[(b * PP + p) * 2 + 1];
    for (int o = 32; o > 0; o >>= 1) {
        s0 += __shfl_xor(s0, o, 64);
        s1 += __shfl_xor(s1, o, 64);
    }
    if (lane == 0) { s_red[4 + wid] = s0; s_red[6 + wid] = s1; }
    __syncthreads();
    if (tid == 0) {
        float c0 = s_red[4] + s_red[5];
        float c1 = s_red[6] + s_red[7];
        int o = ((b * NN + n) * KK1 + k) * CC;
        coeff[o + 0] = __expf(-c0);
        coeff[o + 1] = __expf(-c1);
    }
}

// ---------------------------------------------------------------------------
// Kernel B: transport MLP 10->256->256->128 (tanh,tanh,tanh,exp) per (b,n,m,k)
// + scattering recurrence + final reduction. One block per (b,n,m).
// ---------------------------------------------------------------------------
__global__ __launch_bounds__(256) void transport_kernel(
    const float* __restrict__ phase,
    const float* __restrict__ bcoord,
    const float* __restrict__ boundary,
    const float* __restrict__ bweights,
    const float* __restrict__ velc,
    const float* __restrict__ vweights,
    const float* __restrict__ scat,      // (B,N,K)
    const float* __restrict__ selfscat,  // (B,K,K)
    const float* __restrict__ coeff,     // (B,N,K1,2)
    const float* __restrict__ tw0, const float* __restrict__ tb0,
    const float* __restrict__ tw1, const float* __restrict__ tb1,
    const float* __restrict__ tw2, const float* __restrict__ tb2,
    const float* __restrict__ sw0, const float* __restrict__ sb0,
    const float* __restrict__ sw1, const float* __restrict__ sb1,
    const float* __restrict__ outw,
    float* __restrict__ out)             // (B,N)
{
    __shared__ float tin[KK1 * 10];
    __shared__ float glds[KK1 * WD];
    __shared__ __align__(16) union UU {
        struct { float hT[TWD * 20]; float h1[KK1 * TWD]; } mlp;  // hT padded to 20
        struct {
            float resvs[KK * WD];
            float vstar2[KK * WD];
            float resv[WD];
            float resv2[WD];
            float newv[WD];
            float rwv[KK];
            float rwvs[KK * KK];
            float red[4];
        } sc;
    } u;

    const int tid = threadIdx.x;
    const int blk = blockIdx.x;
    const int b = blk / (NN * MM);
    const int rem = blk % (NN * MM);
    const int n = rem / MM;
    const int m = rem % MM;

    // ---- t_in features: [x(2), vall(2), xp(2), vp(2), coeff(2)] ----
    if (tid < KK1 * 10) {
        int k = tid / 10, f = tid % 10;
        float val;
        if (f < 2)      val = phase[(b * NN + n) * 4 + f];
        else if (f < 4) val = (k == 0) ? phase[(b * NN + n) * 4 + f]
                                       : velc[(b * KK + (k - 1)) * 2 + (f - 2)];
        else if (f < 8) val = bcoord[(b * MM + m) * 4 + (f - 4)];
        else            val = coeff[((b * NN + n) * KK1 + k) * CC + (f - 8)];
        tin[tid] = val;
    }
    __syncthreads();

    // ---- h0: t = tid owns column t; store transposed hT[t][k], stride 20 ----
    {
        const int t = tid;
        const float bias = tb0[t];
        #pragma unroll
        for (int k = 0; k < KK1; ++k) {
            float a = bias;
            #pragma unroll
            for (int i = 0; i < 10; ++i) a += tin[k * 10 + i] * tw0[i * TWD + t];
            u.mlp.hT[t * 20 + k] = fast_tanh(a);
        }
    }
    __syncthreads();

    // ---- h1: each thread owns column t, accumulates 17 rows ----
    {
        const int t = tid;
        float a1[KK1];
        const float bias = tb1[t];
        #pragma unroll
        for (int k = 0; k < KK1; ++k) a1[k] = bias;
        for (int j = 0; j < TWD; ++j) {
            const float wv = tw1[j * TWD + t];
            const float4* h4 = (const float4*)&u.mlp.hT[j * 20];
            #pragma unroll
            for (int q = 0; q < 4; ++q) {
                float4 h = h4[q];
                a1[4 * q + 0] += h.x * wv;
                a1[4 * q + 1] += h.y * wv;
                a1[4 * q + 2] += h.z * wv;
                a1[4 * q + 3] += h.w * wv;
            }
            a1[16] += u.mlp.hT[j * 20 + 16] * wv;
        }
        #pragma unroll
        for (int k = 0; k < KK1; ++k) u.mlp.h1[k * TWD + t] = fast_tanh(a1[k]);
    }
    __syncthreads();

    // ---- h2 + g = exp(tanh(.)): rows split 9 (tid<128) / 8 (tid>=128) ----
    {
        const int w = tid & 127;
        const int k0 = (tid < 128) ? 0 : 9;
        const float bias = tb2[w];
        float acc[9];
        #pragma unroll
        for (int q = 0; q < 9; ++q) acc[q] = bias;
        for (int j4 = 0; j4 < TWD / 4; ++j4) {
            const float w0 = tw2[(4 * j4 + 0) * WD + w];
            const float w1 = tw2[(4 * j4 + 1) * WD + w];
            const float w2 = tw2[(4 * j4 + 2) * WD + w];
            const float w3 = tw2[(4 * j4 + 3) * WD + w];
            #pragma unroll
            for (int q = 0; q < 9; ++q) {
                int k = k0 + q;
                if (k < KK1) {
                    const float4 h = *(const float4*)&u.mlp.h1[k * TWD + 4 * j4];
                    acc[q] += h.x * w0 + h.y * w1 + h.z * w2 + h.w * w3;
                }
            }
        }
        #pragma unroll
        for (int q = 0; q < 9; ++q) {
            int k = k0 + q;
            if (k < KK1) glds[k * WD + w] = __expf(fast_tanh(acc[q]));
        }
    }
    __syncthreads();

    // ---- scattering weights ----
    if (tid < KK) u.sc.rwv[tid] = (1.0f - scat[(b * NN + n) * KK + tid]) * vweights[b * KK + tid];
    {
        int i = tid >> 4, j = tid & 15;
        u.sc.rwvs[tid] = (1.0f - selfscat[(b * KK + i) * KK + j]) * vweights[b * KK + j];
    }
    __syncthreads();

    // ---- res_v and res_vs ----
    if (tid < WD) {
        float a = 0.0f;
        #pragma unroll
        for (int k = 0; k < KK; ++k) a += u.sc.rwv[k] * glds[(1 + k) * WD + tid];
        u.sc.resv[tid] = a;
    }
    for (int idx = tid; idx < KK * WD; idx += 256) {
        int i = idx >> 7, w = idx & 127;
        float a = 0.0f;
        #pragma unroll
        for (int j = 0; j < KK; ++j) a += u.sc.rwvs[i * KK + j] * glds[(1 + j) * WD + w];
        u.sc.resvs[i * WD + w] = a;
    }
    __syncthreads();

    // ---- sw0 matvecs: vstar2[k][i] and newv[i] ----
    {
        const int i = tid & 127;
        const int kh = tid >> 7;
        const float bias = sb0[i];
        float acc[8];
        #pragma unroll
        for (int q = 0; q < 8; ++q) acc[q] = bias;
        float accv = bias;
        const float4* sw0r = (const float4*)&sw0[i * WD];
        for (int w4 = 0; w4 < WD / 4; ++w4) {
            const float4 s = sw0r[w4];
            #pragma unroll
            for (int q = 0; q < 8; ++q) {
                const int k = kh + 2 * q;
                const float4 r = *(const float4*)&u.sc.resvs[k * WD + 4 * w4];
                acc[q] += s.x * r.x + s.y * r.y + s.z * r.z + s.w * r.w;
            }
            if (tid < 128) {
                const float4 r = *(const float4*)&u.sc.resv[4 * w4];
                accv += s.x * r.x + s.y * r.y + s.z * r.z + s.w * r.w;
            }
        }
        #pragma unroll
        for (int q = 0; q < 8; ++q) {
            const int k = kh + 2 * q;
            u.sc.vstar2[k * WD + i] = glds[(1 + k) * WD + i] + fast_tanh(acc[q]);
        }
        if (tid < 128) u.sc.newv[i] = glds[0 * WD + i] + fast_tanh(accv);
    }
    __syncthreads();

    // ---- res_v2 over vstar2 ----
    if (tid < WD) {
        float a = 0.0f;
        #pragma unroll
        for (int k = 0; k < KK; ++k) a += u.sc.rwv[k] * u.sc.vstar2[k * WD + tid];
        u.sc.resv2[tid] = a;
    }
    __syncthreads();

    // ---- green, gdot, accumulate output ----
    float part = 0.0f;
    if (tid < WD) {
        const int i = tid;
        float a = sb1[i];
        const float4* sw1r = (const float4*)&sw1[i * WD];
        #pragma unroll
        for (int w4 = 0; w4 < WD / 4; ++w4) {
            const float4 s = sw1r[w4];
            const float4 r = *(const float4*)&u.sc.resv2[4 * w4];
            a += s.x * r.x + s.y * r.y + s.z * r.z + s.w * r.w;
        }
        const float green = u.sc.newv[i] + fast_tanh(a);
        part = green * outw[i];
    }
    for (int o = 32; o > 0; o >>= 1) part += __shfl_xor(part, o, 64);
    if ((tid & 63) == 0) u.sc.red[tid >> 6] = part;
    __syncthreads();
    if (tid == 0) {
        const float gdot = u.sc.red[0] + u.sc.red[1];
        const float bb = boundary[b * MM + m] * bweights[b * MM + m];
        atomicAdd(&out[b * NN + n], gdot * bb);
    }
}

extern "C" void kernel_launch(void* const* d_in, const int* in_sizes, int n_in,
                              void* d_out, int out_size, void* d_ws, size_t ws_size,
                              hipStream_t stream) {
    const float* phase    = (const float*)d_in[0];
    const float* bcoord   = (const float*)d_in[1];
    const float* boundary = (const float*)d_in[2];
    const float* bweights = (const float*)d_in[3];
    const float* posc     = (const float*)d_in[4];
    const float* sigma    = (const float*)d_in[5];
    const float* velc     = (const float*)d_in[6];
    const float* vweights = (const float*)d_in[7];
    const float* scat     = (const float*)d_in[8];
    const float* selfscat = (const float*)d_in[9];
    const float* aw0 = (const float*)d_in[10];
    const float* ab0 = (const float*)d_in[11];
    const float* aw1 = (const float*)d_in[12];
    const float* ab1 = (const float*)d_in[13];
    const float* aw2 = (const float*)d_in[14];
    const float* ab2 = (const float*)d_in[15];
    const float* tw0 = (const float*)d_in[16];
    const float* tb0 = (const float*)d_in[17];
    const float* tw1 = (const float*)d_in[18];
    const float* tb1 = (const float*)d_in[19];
    const float* tw2 = (const float*)d_in[20];
    const float* tb2 = (const float*)d_in[21];
    const float* sw0 = (const float*)d_in[22];
    const float* sb0 = (const float*)d_in[23];
    const float* sw1 = (const float*)d_in[24];
    const float* sb1 = (const float*)d_in[25];
    const float* outw = (const float*)d_in[26];

    float* out = (float*)d_out;
    float* coeff = (float*)d_ws;  // B*N*K1*C = 4352 floats

    hipMemsetAsync(d_out, 0, (size_t)out_size * sizeof(float), stream);

    attn_kernel<<<BB * NN * KK1, 128, 0, stream>>>(
        phase, posc, sigma, velc, aw0, ab0, aw1, ab1, aw2, ab2, coeff);

    transport_kernel<<<BB * NN * MM, 256, 0, stream>>>(
        phase, bcoord, boundary, bweights, velc, vweights, scat, selfscat, coeff,
        tw0, tb0, tw1, tb1, tw2, tb2, sw0, sb0, sw1, sb1, outw, out);
}

// Round 2
// 426.961 us; speedup vs baseline: 2.4744x; 2.4744x over previous
//
#include <hip/hip_runtime.h>
#include <hip/hip_bf16.h>

#define BB 4
#define NN 32
#define MM 64
#define KK 16
#define KK1 17
#define PP 128
#define CC 2
#define AWD 64

typedef unsigned short ushort_t;
typedef unsigned int uint32;
typedef __attribute__((ext_vector_type(8))) short bhalf8;
typedef __attribute__((ext_vector_type(4))) float floatx4;

__device__ __forceinline__ float fast_tanh(float x) {
    float e = __expf(2.0f * x);
    return 1.0f - 2.0f / (e + 1.0f);
}
__device__ __forceinline__ ushort_t f2b(float f) {
    uint32 u = __float_as_uint(f);
    return (ushort_t)((u + 0x7FFFu + ((u >> 16) & 1u)) >> 16);  // RNE bf16
}
__device__ __forceinline__ float b2f(ushort_t h) {
    return __uint_as_float(((uint32)h) << 16);
}

// ---------------------------------------------------------------------------
// Prep: convert weights to bf16 B-operand layouts (W^T, k-contiguous) in ws
// W0t[256][32] (tw0^T, k-pad 10->32), W1t[256][256], W2t[128][256],
// S0t[128][128]=sw0 row-major, S1t[128][128]=sw1 row-major
// ---------------------------------------------------------------------------
__global__ void prep_kernel(const float* __restrict__ tw0, const float* __restrict__ tw1,
                            const float* __restrict__ tw2, const float* __restrict__ sw0,
                            const float* __restrict__ sw1,
                            ushort_t* __restrict__ W0t, ushort_t* __restrict__ W1t,
                            ushort_t* __restrict__ W2t, ushort_t* __restrict__ S0t,
                            ushort_t* __restrict__ S1t) {
    int i = blockIdx.x * 256 + threadIdx.x;
    if (i < 8192) {
        int nn = i >> 5, k = i & 31;
        W0t[i] = (k < 10) ? f2b(tw0[k * 256 + nn]) : (ushort_t)0;
    } else if (i < 73728) {
        int j = i - 8192; int nn = j >> 8, k = j & 255;
        W1t[j] = f2b(tw1[k * 256 + nn]);
    } else if (i < 106496) {
        int j = i - 73728; int nn = j >> 8, k = j & 255;
        W2t[j] = f2b(tw2[k * 128 + nn]);
    } else if (i < 122880) {
        S0t[i - 106496] = f2b(sw0[i - 106496]);
    } else if (i < 139264) {
        S1t[i - 122880] = f2b(sw1[i - 122880]);
    }
}

// ---------------------------------------------------------------------------
// Kernel A: attention MLP + masked softmax + coeff (unchanged from R1)
// ---------------------------------------------------------------------------
__global__ __launch_bounds__(128) void attn_kernel(
    const float* __restrict__ phase, const float* __restrict__ posc,
    const float* __restrict__ sigma, const float* __restrict__ velc,
    const float* __restrict__ aw0, const float* __restrict__ ab0,
    const float* __restrict__ aw1, const float* __restrict__ ab1,
    const float* __restrict__ aw2, const float* __restrict__ ab2,
    float* __restrict__ coeff)
{
    __shared__ __align__(16) float s_aw0[6 * AWD];
    __shared__ __align__(16) float s_aw1t[AWD * AWD];
    __shared__ float s_ab0[AWD];
    __shared__ float s_ab1[AWD];
    __shared__ float s_aw2[AWD];
    __shared__ float s_red[8];

    const int tid = threadIdx.x;
    const int blk = blockIdx.x;
    const int b = blk / (NN * KK1);
    const int rem = blk % (NN * KK1);
    const int n = rem / KK1;
    const int k = rem % KK1;

    for (int idx = tid; idx < 6 * AWD; idx += 128) s_aw0[idx] = aw0[idx];
    for (int idx = tid; idx < AWD * AWD; idx += 128) {
        int j = idx >> 6, i = idx & 63;
        s_aw1t[i * AWD + j] = aw1[idx];
    }
    if (tid < AWD) { s_ab0[tid] = ab0[tid]; s_ab1[tid] = ab1[tid]; s_aw2[tid] = aw2[tid]; }
    __syncthreads();

    const int p = tid;
    const float x0 = phase[(b * NN + n) * 4 + 0];
    const float x1 = phase[(b * NN + n) * 4 + 1];
    float va0, va1;
    if (k == 0) { va0 = phase[(b * NN + n) * 4 + 2]; va1 = phase[(b * NN + n) * 4 + 3]; }
    else { va0 = velc[(b * KK + (k - 1)) * 2 + 0]; va1 = velc[(b * KK + (k - 1)) * 2 + 1]; }
    const float inv = rsqrtf(va0 * va0 + va1 * va1 + 1e-16f);
    const float ag0 = va0 * inv, ag1 = va1 * inv;
    const float px = posc[(b * PP + p) * 2 + 0];
    const float py = posc[(b * PP + p) * 2 + 1];
    const float r0 = x0 - px, r1 = x1 - py;
    const float rd = sqrtf(r0 * r0 + r1 * r1 + 1e-16f);
    const float pl = r0 * ag0 + r1 * ag1;
    const float al = pl / (rd + 1e-8f);

    float f[6] = {x0, x1, va0, va1, al, pl};

    float h0[AWD];
    #pragma unroll 4
    for (int i = 0; i < AWD; ++i) {
        float a = s_ab0[i];
        #pragma unroll
        for (int j = 0; j < 6; ++j) a += f[j] * s_aw0[j * AWD + i];
        h0[i] = fast_tanh(a);
    }

    float logit = ab2[0];
    #pragma unroll 2
    for (int i = 0; i < AWD; ++i) {
        float a = s_ab1[i];
        const float4* w4 = (const float4*)&s_aw1t[i * AWD];
        #pragma unroll
        for (int j4 = 0; j4 < AWD / 4; ++j4) {
            float4 w = w4[j4];
            a += h0[4 * j4 + 0] * w.x + h0[4 * j4 + 1] * w.y +
                 h0[4 * j4 + 2] * w.z + h0[4 * j4 + 3] * w.w;
        }
        logit += fast_tanh(a) * s_aw2[i];
    }

    const float ml = (pl > 0.0f) ? logit : -1e30f;
    const int lane = tid & 63, wid = tid >> 6;

    float mv = ml;
    for (int o = 32; o > 0; o >>= 1) mv = fmaxf(mv, __shfl_xor(mv, o, 64));
    if (lane == 0) s_red[wid] = mv;
    __syncthreads();
    mv = fmaxf(s_red[0], s_red[1]);

    const float ew = __expf(ml - mv);
    float sv = ew;
    for (int o = 32; o > 0; o >>= 1) sv += __shfl_xor(sv, o, 64);
    if (lane == 0) s_red[2 + wid] = sv;
    __syncthreads();
    sv = s_red[2] + s_red[3];
    const float attn = ew / sv;

    float s0 = attn * sigma[(b * PP + p) * 2 + 0];
    float s1 = attn * sigma[(b * PP + p) * 2 + 1];
    for (int o = 32; o > 0; o >>= 1) { s0 += __shfl_xor(s0, o, 64); s1 += __shfl_xor(s1, o, 64); }
    if (lane == 0) { s_red[4 + wid] = s0; s_red[6 + wid] = s1; }
    __syncthreads();
    if (tid == 0) {
        float c0 = s_red[4] + s_red[5];
        float c1 = s_red[6] + s_red[7];
        int o = ((b * NN + n) * KK1 + k) * CC;
        coeff[o + 0] = __expf(-c0);
        coeff[o + 1] = __expf(-c1);
    }
}

// ---------------------------------------------------------------------------
// Kernel B: MFMA transport. One block per (b, n, 2 m's). 256 thr = 4 waves.
// Rows r = ml*17 + k (34 valid, padded to 48 = 3 M-tiles of 16).
// Stages: A0 -> L0 -> L1 -> L2(gTs/gv) -> resvs -> sw0 -> resv2 -> green.
// ---------------------------------------------------------------------------
#define HS   264   // h0A/h1A element stride (256 + 8 pad, keeps 16B align, 2-way banks)
#define GTS  48    // gTs stride (rows (m,j), padded; rows 32-47 zeroed)
#define AS2S 136   // As2/A3 stride (128 + 8)
#define V2S  32    // v2T stride (exactly K=32)
#define ASS  32    // A_s stride

// LDS map (ushort indices unless F_ = float indices). X1=[0,12672u) X2=[12672,25344u) X3=A0
#define U_H0A  0
#define U_GTS  0
#define F_GV   3072   // byte 12288
#define F_NEWV 3328   // byte 13312
#define U_A2S  7168   // byte 14336
#define U_A3   7680   // byte 15360 .. 19712
#define U_H1A  12672
#define U_AS2  12672
#define U_V2T  19200  // byte 38400 .. 46592
#define U_A0   25344  // byte 50688, 1536u
#define U_AS   25344  // alias A0 (A0 dead after L0)
#define F_RED  13440  // byte 53760
#define F_BBW  13448

__global__ __launch_bounds__(256, 2) void transport_kernel(
    const float* __restrict__ phase, const float* __restrict__ bcoord,
    const float* __restrict__ boundary, const float* __restrict__ bweights,
    const float* __restrict__ velc, const float* __restrict__ vweights,
    const float* __restrict__ scat, const float* __restrict__ selfscat,
    const float* __restrict__ coeff,
    const ushort_t* __restrict__ W0t, const ushort_t* __restrict__ W1t,
    const ushort_t* __restrict__ W2t, const ushort_t* __restrict__ S0t,
    const ushort_t* __restrict__ S1t,
    const float* __restrict__ tb0, const float* __restrict__ tb1,
    const float* __restrict__ tb2, const float* __restrict__ sb0,
    const float* __restrict__ sb1, const float* __restrict__ outw,
    float* __restrict__ out)
{
    __shared__ __align__(16) ushort_t smem[26912];
    float* smf = (float*)smem;

    const int tid = threadIdx.x;
    const int wave = tid >> 6;
    const int lane = tid & 63;
    const int lrow = lane & 15;   // A row / B col / C col within tile
    const int lkg  = lane >> 4;   // k-group (8 elems each) / C row-quad

    const int blk = blockIdx.x;
    const int b  = blk >> 10;
    const int n  = (blk >> 5) & 31;
    const int mg = blk & 31;
    const int m0 = mg * 2;

    if (tid < 2)
        smf[F_BBW + tid] = boundary[b * MM + m0 + tid] * bweights[b * MM + m0 + tid];

    // ---- build A0: rows 48 x cols 32 bf16 (rows>=34 and cols>=10 zero) ----
    for (int idx = tid; idx < 48 * 32; idx += 256) {
        int r = idx >> 5, c = idx & 31;
        float val = 0.0f;
        if (r < 34 && c < 10) {
            int ml = (r >= 17);
            int k = r - ml * 17;
            int m = m0 + ml;
            if (c < 2)      val = phase[(b * NN + n) * 4 + c];
            else if (c < 4) val = (k == 0) ? phase[(b * NN + n) * 4 + c]
                                           : velc[(b * KK + k - 1) * 2 + (c - 2)];
            else if (c < 8) val = bcoord[(b * MM + m) * 4 + (c - 4)];
            else            val = coeff[((b * NN + n) * KK1 + k) * CC + (c - 8)];
        }
        smem[U_A0 + idx] = f2b(val);
    }
    __syncthreads();

    // ---- L0: h0 = tanh(A0 @ W0t + tb0) -> h0A bf16 ----
    {
        float b0v[4];
        #pragma unroll
        for (int j = 0; j < 4; ++j) b0v[j] = tb0[(4 * wave + j) * 16 + lrow];
        for (int mt = 0; mt < 3; ++mt) {
            bhalf8 a = *(const bhalf8*)&smem[U_A0 + (mt * 16 + lrow) * 32 + lkg * 8];
            #pragma unroll
            for (int j = 0; j < 4; ++j) {
                int nt = 4 * wave + j;
                bhalf8 bf = *(const bhalf8*)(W0t + (nt * 16 + lrow) * 32 + lkg * 8);
                floatx4 c = {0.f, 0.f, 0.f, 0.f};
                c = __builtin_amdgcn_mfma_f32_16x16x32_bf16(a, bf, c, 0, 0, 0);
                #pragma unroll
                for (int q = 0; q < 4; ++q) {
                    int row = mt * 16 + lkg * 4 + q;
                    smem[U_H0A + row * HS + nt * 16 + lrow] = f2b(fast_tanh(c[q] + b0v[j]));
                }
            }
        }
    }
    __syncthreads();

    // ---- A_s build (over dead A0): rows 0-15 rwvs, row 16 rwv; cols 16-31 zero ----
    for (int idx = tid; idx < 17 * 32; idx += 256) {
        int i = idx >> 5, c = idx & 31;
        float val = 0.0f;
        if (c < 16) {
            float vw = vweights[b * KK + c];
            val = (i < 16) ? (1.0f - selfscat[(b * KK + i) * KK + c]) * vw
                           : (1.0f - scat[(b * NN + n) * KK + c]) * vw;
        }
        smem[U_AS + i * ASS + c] = f2b(val);
    }
    // ---- L1: h1 = tanh(h0A @ W1t + tb1) -> h1A bf16 ----
    {
        float b1v[4];
        #pragma unroll
        for (int j = 0; j < 4; ++j) b1v[j] = tb1[(4 * wave + j) * 16 + lrow];
        for (int mt = 0; mt < 3; ++mt) {
            bhalf8 a[8];
            #pragma unroll
            for (int ks = 0; ks < 8; ++ks)
                a[ks] = *(const bhalf8*)&smem[U_H0A + (mt * 16 + lrow) * HS + ks * 32 + lkg * 8];
            #pragma unroll
            for (int j = 0; j < 4; ++j) {
                int nt = 4 * wave + j;
                const ushort_t* bp = W1t + (nt * 16 + lrow) * 256 + lkg * 8;
                floatx4 c = {0.f, 0.f, 0.f, 0.f};
                #pragma unroll
                for (int ks = 0; ks < 8; ++ks) {
                    bhalf8 bf = *(const bhalf8*)(bp + ks * 32);
                    c = __builtin_amdgcn_mfma_f32_16x16x32_bf16(a[ks], bf, c, 0, 0, 0);
                }
                #pragma unroll
                for (int q = 0; q < 4; ++q) {
                    int row = mt * 16 + lkg * 4 + q;
                    smem[U_H1A + row * HS + nt * 16 + lrow] = f2b(fast_tanh(c[q] + b1v[j]));
                }
            }
        }
    }
    __syncthreads();

    // ---- L2 stage: zero gTs pad rows, build A2s, g = exp(tanh(h1A@W2t+tb2)) ----
    for (int idx = tid; idx < 128 * 16; idx += 256) {
        int w = idx >> 4, r = 32 + (idx & 15);
        smem[U_GTS + w * GTS + r] = 0;
    }
    for (int idx = tid; idx < 16 * 32; idx += 256) {
        int r = idx >> 5, c = idx & 31;
        smem[U_A2S + idx] = ((c >> 4) == r) ? smem[U_AS + 16 * ASS + (c & 15)] : (ushort_t)0;
    }
    {
        float b2v[2];
        #pragma unroll
        for (int j = 0; j < 2; ++j) b2v[j] = tb2[(2 * wave + j) * 16 + lrow];
        for (int mt = 0; mt < 3; ++mt) {
            bhalf8 a[8];
            #pragma unroll
            for (int ks = 0; ks < 8; ++ks)
                a[ks] = *(const bhalf8*)&smem[U_H1A + (mt * 16 + lrow) * HS + ks * 32 + lkg * 8];
            #pragma unroll
            for (int j = 0; j < 2; ++j) {
                int nt = 2 * wave + j;
                const ushort_t* bp = W2t + (nt * 16 + lrow) * 256 + lkg * 8;
                floatx4 c = {0.f, 0.f, 0.f, 0.f};
                #pragma unroll
                for (int ks = 0; ks < 8; ++ks) {
                    bhalf8 bf = *(const bhalf8*)(bp + ks * 32);
                    c = __builtin_amdgcn_mfma_f32_16x16x32_bf16(a[ks], bf, c, 0, 0, 0);
                }
                #pragma unroll
                for (int q = 0; q < 4; ++q) {
                    int row = mt * 16 + lkg * 4 + q;
                    if (row < 34) {
                        int ml = (row >= 17);
                        int k = row - ml * 17;
                        int col = nt * 16 + lrow;
                        float g = __expf(fast_tanh(c[q] + b2v[j]));
                        if (k == 0) smf[F_GV + ml * 128 + col] = g;
                        else        smem[U_GTS + col * GTS + ml * 16 + (k - 1)] = f2b(g);
                    }
                }
            }
        }
    }
    __syncthreads();

    // ---- resvs: [rwvs;rwv](17x16,K=32) @ gTs -> As2 rows (m: [resv; resvs]) ----
    {
        bhalf8 a0 = *(const bhalf8*)&smem[U_AS + lrow * ASS + lkg * 8];
        bhalf8 a1 = *(const bhalf8*)&smem[U_AS + (16 + lrow) * ASS + lkg * 8];
        for (int m = 0; m < 2; ++m) {
            #pragma unroll
            for (int j = 0; j < 2; ++j) {
                int nt = 2 * wave + j;
                bhalf8 bf = *(const bhalf8*)&smem[U_GTS + (nt * 16 + lrow) * GTS + m * 16 + lkg * 8];
                #pragma unroll
                for (int mt = 0; mt < 2; ++mt) {
                    floatx4 c = {0.f, 0.f, 0.f, 0.f};
                    c = __builtin_amdgcn_mfma_f32_16x16x32_bf16(mt ? a1 : a0, bf, c, 0, 0, 0);
                    #pragma unroll
                    for (int q = 0; q < 4; ++q) {
                        int ic = mt * 16 + lkg * 4 + q;
                        if (ic < 17) {
                            int r2 = (ic == 16) ? m * 17 : m * 17 + 1 + ic;
                            smem[U_AS2 + r2 * AS2S + nt * 16 + lrow] = f2b(c[q]);
                        }
                    }
                }
            }
        }
    }
    __syncthreads();

    // ---- sw0: tanh(As2 @ S0t + sb0); i2==0 -> newv (fp32), else v2T bf16 ----
    {
        float s0v[2];
        #pragma unroll
        for (int j = 0; j < 2; ++j) s0v[j] = sb0[(2 * wave + j) * 16 + lrow];
        for (int mt = 0; mt < 3; ++mt) {
            bhalf8 a[4];
            #pragma unroll
            for (int ks = 0; ks < 4; ++ks)
                a[ks] = *(const bhalf8*)&smem[U_AS2 + (mt * 16 + lrow) * AS2S + ks * 32 + lkg * 8];
            #pragma unroll
            for (int j = 0; j < 2; ++j) {
                int nt = 2 * wave + j;
                const ushort_t* bp = S0t + (nt * 16 + lrow) * 128 + lkg * 8;
                floatx4 c = {0.f, 0.f, 0.f, 0.f};
                #pragma unroll
                for (int ks = 0; ks < 4; ++ks) {
                    bhalf8 bf = *(const bhalf8*)(bp + ks * 32);
                    c = __builtin_amdgcn_mfma_f32_16x16x32_bf16(a[ks], bf, c, 0, 0, 0);
                }
                #pragma unroll
                for (int q = 0; q < 4; ++q) {
                    int r2 = mt * 16 + lkg * 4 + q;
                    if (r2 < 34) {
                        int m = (r2 >= 17);
                        int i2 = r2 - m * 17;
                        int col = nt * 16 + lrow;
                        float val = fast_tanh(c[q] + s0v[j]);
                        if (i2 == 0) {
                            smf[F_NEWV + m * 128 + col] = smf[F_GV + m * 128 + col] + val;
                        } else {
                            int j2 = i2 - 1;
                            smem[U_V2T + col * V2S + m * 16 + j2] =
                                f2b(b2f(smem[U_GTS + col * GTS + m * 16 + j2]) + val);
                        }
                    }
                }
            }
        }
    }
    __syncthreads();

    // ---- resv2: block-diag rwv (A2s, K=32) @ v2T -> A3 bf16 ----
    {
        bhalf8 a = *(const bhalf8*)&smem[U_A2S + lrow * 32 + lkg * 8];
        #pragma unroll
        for (int j = 0; j < 2; ++j) {
            int nt = 2 * wave + j;
            bhalf8 bf = *(const bhalf8*)&smem[U_V2T + (nt * 16 + lrow) * V2S + lkg * 8];
            floatx4 c = {0.f, 0.f, 0.f, 0.f};
            c = __builtin_amdgcn_mfma_f32_16x16x32_bf16(a, bf, c, 0, 0, 0);
            #pragma unroll
            for (int q = 0; q < 4; ++q) {
                int r = lkg * 4 + q;
                smem[U_A3 + r * AS2S + nt * 16 + lrow] = f2b(c[q]);
            }
        }
    }
    __syncthreads();

    // ---- green: newv + tanh(A3 @ S1t + sb1); dot with outw, weight bbw ----
    float acc = 0.0f;
    {
        float s1v[2], owv[2];
        #pragma unroll
        for (int j = 0; j < 2; ++j) {
            s1v[j] = sb1[(2 * wave + j) * 16 + lrow];
            owv[j] = outw[(2 * wave + j) * 16 + lrow];
        }
        bhalf8 a[4];
        #pragma unroll
        for (int ks = 0; ks < 4; ++ks)
            a[ks] = *(const bhalf8*)&smem[U_A3 + lrow * AS2S + ks * 32 + lkg * 8];
        #pragma unroll
        for (int j = 0; j < 2; ++j) {
            int nt = 2 * wave + j;
            const ushort_t* bp = S1t + (nt * 16 + lrow) * 128 + lkg * 8;
            floatx4 c = {0.f, 0.f, 0.f, 0.f};
            #pragma unroll
            for (int ks = 0; ks < 4; ++ks) {
                bhalf8 bf = *(const bhalf8*)(bp + ks * 32);
                c = __builtin_amdgcn_mfma_f32_16x16x32_bf16(a[ks], bf, c, 0, 0, 0);
            }
            #pragma unroll
            for (int q = 0; q < 4; ++q) {
                int r = lkg * 4 + q;
                if (r < 2) {
                    int col = nt * 16 + lrow;
                    float green = smf[F_NEWV + r * 128 + col] + fast_tanh(c[q] + s1v[j]);
                    acc += green * owv[j] * smf[F_BBW + r];
                }
            }
        }
    }
    for (int o = 32; o > 0; o >>= 1) acc += __shfl_xor(acc, o, 64);
    if (lane == 0) smf[F_RED + wave] = acc;
    __syncthreads();
    if (tid == 0) {
        float tot = smf[F_RED + 0] + smf[F_RED + 1] + smf[F_RED + 2] + smf[F_RED + 3];
        atomicAdd(&out[b * NN + n], tot);
    }
}

extern "C" void kernel_launch(void* const* d_in, const int* in_sizes, int n_in,
                              void* d_out, int out_size, void* d_ws, size_t ws_size,
                              hipStream_t stream) {
    const float* phase    = (const float*)d_in[0];
    const float* bcoord   = (const float*)d_in[1];
    const float* boundary = (const float*)d_in[2];
    const float* bweights = (const float*)d_in[3];
    const float* posc     = (const float*)d_in[4];
    const float* sigma    = (const float*)d_in[5];
    const float* velc     = (const float*)d_in[6];
    const float* vweights = (const float*)d_in[7];
    const float* scat     = (const float*)d_in[8];
    const float* selfscat = (const float*)d_in[9];
    const float* aw0 = (const float*)d_in[10];
    const float* ab0 = (const float*)d_in[11];
    const float* aw1 = (const float*)d_in[12];
    const float* ab1 = (const float*)d_in[13];
    const float* aw2 = (const float*)d_in[14];
    const float* ab2 = (const float*)d_in[15];
    const float* tw0 = (const float*)d_in[16];
    const float* tb0 = (const float*)d_in[17];
    const float* tw1 = (const float*)d_in[18];
    const float* tb1 = (const float*)d_in[19];
    const float* tw2 = (const float*)d_in[20];
    const float* tb2 = (const float*)d_in[21];
    const float* sw0 = (const float*)d_in[22];
    const float* sb0 = (const float*)d_in[23];
    const float* sw1 = (const float*)d_in[24];
    const float* sb1 = (const float*)d_in[25];
    const float* outw = (const float*)d_in[26];

    float* out = (float*)d_out;
    char* ws = (char*)d_ws;
    float* coeff = (float*)ws;                      // 17408 B
    ushort_t* W0t = (ushort_t*)(ws + 17408);        // 16384 B
    ushort_t* W1t = (ushort_t*)(ws + 33792);        // 131072 B
    ushort_t* W2t = (ushort_t*)(ws + 164864);       // 65536 B
    ushort_t* S0t = (ushort_t*)(ws + 230400);       // 32768 B
    ushort_t* S1t = (ushort_t*)(ws + 263168);       // 32768 B -> 295936 total

    hipMemsetAsync(d_out, 0, (size_t)out_size * sizeof(float), stream);

    prep_kernel<<<544, 256, 0, stream>>>(tw0, tw1, tw2, sw0, sw1, W0t, W1t, W2t, S0t, S1t);

    attn_kernel<<<BB * NN * KK1, 128, 0, stream>>>(
        phase, posc, sigma, velc, aw0, ab0, aw1, ab1, aw2, ab2, coeff);

    transport_kernel<<<BB * NN * 32, 256, 0, stream>>>(
        phase, bcoord, boundary, bweights, velc, vweights, scat, selfscat, coeff,
        W0t, W1t, W2t, S0t, S1t, tb0, tb1, tb2, sb0, sb1, outw, out);
}

// Round 3
// 334.506 us; speedup vs baseline: 3.1583x; 1.2764x over previous
//
#include <hip/hip_runtime.h>
#include <hip/hip_bf16.h>

#define BB 4
#define NN 32
#define MM 64
#define KK 16
#define KK1 17
#define PP 128
#define CC 2

typedef unsigned short ushort_t;
typedef unsigned int uint32;
typedef __attribute__((ext_vector_type(8))) short bhalf8;
typedef __attribute__((ext_vector_type(4))) float floatx4;

__device__ __forceinline__ float fast_tanh(float x) {
    float e = __expf(2.0f * x);
    return 1.0f - 2.0f / (e + 1.0f);
}
__device__ __forceinline__ ushort_t f2b(float f) {
    uint32 u = __float_as_uint(f);
    return (ushort_t)((u + 0x8000u) >> 16);  // round-half-up bf16
}
__device__ __forceinline__ float b2f(ushort_t h) {
    return __uint_as_float(((uint32)h) << 16);
}

// ---------------------------------------------------------------------------
// Prep: all weights -> bf16 B-operand layouts (W^T, k-contiguous) in ws
// ---------------------------------------------------------------------------
__global__ void prep_kernel(const float* __restrict__ tw0, const float* __restrict__ tw1,
                            const float* __restrict__ tw2, const float* __restrict__ sw0,
                            const float* __restrict__ sw1, const float* __restrict__ aw0,
                            const float* __restrict__ aw1,
                            ushort_t* __restrict__ W0t, ushort_t* __restrict__ W1t,
                            ushort_t* __restrict__ W2t, ushort_t* __restrict__ S0t,
                            ushort_t* __restrict__ S1t, ushort_t* __restrict__ W0a,
                            ushort_t* __restrict__ W1a) {
    int i = blockIdx.x * 256 + threadIdx.x;
    if (i < 8192) {
        int nn = i >> 5, k = i & 31;
        W0t[i] = (k < 10) ? f2b(tw0[k * 256 + nn]) : (ushort_t)0;
    } else if (i < 73728) {
        int j = i - 8192; int nn = j >> 8, k = j & 255;
        W1t[j] = f2b(tw1[k * 256 + nn]);
    } else if (i < 106496) {
        int j = i - 73728; int nn = j >> 8, k = j & 255;
        W2t[j] = f2b(tw2[k * 128 + nn]);
    } else if (i < 122880) {
        S0t[i - 106496] = f2b(sw0[i - 106496]);
    } else if (i < 139264) {
        S1t[i - 122880] = f2b(sw1[i - 122880]);
    } else if (i < 141312) {
        int j = i - 139264; int nn = j >> 5, k = j & 31;
        W0a[j] = (k < 6) ? f2b(aw0[k * 64 + nn]) : (ushort_t)0;
    } else if (i < 145408) {
        int j = i - 141312; int nn = j >> 6, k = j & 63;
        W1a[j] = f2b(aw1[k * 64 + nn]);
    }
}

// ---------------------------------------------------------------------------
// Kernel A (MFMA): block per (b,n,k); 128 thr = 2 waves; M=128 p-rows.
// L1: 128x64 K=32(pad6)  L2: 128x64 K=64 -> logits via aw2 dot in C-space.
// ---------------------------------------------------------------------------
#define AH0S 72   // h0 LDS stride (64+8)

__global__ __launch_bounds__(128) void attn_kernel(
    const float* __restrict__ phase, const float* __restrict__ posc,
    const float* __restrict__ sigma, const float* __restrict__ velc,
    const ushort_t* __restrict__ W0a, const ushort_t* __restrict__ W1a,
    const float* __restrict__ ab0, const float* __restrict__ ab1,
    const float* __restrict__ aw2, const float* __restrict__ ab2,
    float* __restrict__ coeff)
{
    __shared__ __align__(16) ushort_t sA0[128 * 32];
    __shared__ __align__(16) ushort_t sH0[128 * AH0S];
    __shared__ float sPL[128];
    __shared__ float sLG[128];
    __shared__ float s_red[8];

    const int tid = threadIdx.x;
    const int wave = tid >> 6;
    const int lane = tid & 63;
    const int lrow = lane & 15;
    const int lkg  = lane >> 4;

    const int blk = blockIdx.x;
    const int b = blk / (NN * KK1);
    const int rem = blk % (NN * KK1);
    const int n = rem / KK1;
    const int k = rem % KK1;

    // ---- features for row p = tid (fp32), write A0 row in bf16 ----
    {
        const int p = tid;
        const float x0 = phase[(b * NN + n) * 4 + 0];
        const float x1 = phase[(b * NN + n) * 4 + 1];
        float va0, va1;
        if (k == 0) { va0 = phase[(b * NN + n) * 4 + 2]; va1 = phase[(b * NN + n) * 4 + 3]; }
        else { va0 = velc[(b * KK + (k - 1)) * 2 + 0]; va1 = velc[(b * KK + (k - 1)) * 2 + 1]; }
        const float inv = rsqrtf(va0 * va0 + va1 * va1 + 1e-16f);
        const float ag0 = va0 * inv, ag1 = va1 * inv;
        const float px = posc[(b * PP + p) * 2 + 0];
        const float py = posc[(b * PP + p) * 2 + 1];
        const float r0 = x0 - px, r1 = x1 - py;
        const float rd = sqrtf(r0 * r0 + r1 * r1 + 1e-16f);
        const float pl = r0 * ag0 + r1 * ag1;
        const float al = pl / (rd + 1e-8f);
        sPL[p] = pl;
        float feat[6] = {x0, x1, va0, va1, al, pl};
        #pragma unroll
        for (int c = 0; c < 6; ++c) sA0[p * 32 + c] = f2b(feat[c]);
        #pragma unroll
        for (int c = 6; c < 32; ++c) sA0[p * 32 + c] = 0;
    }
    __syncthreads();

    // ---- L1: h0 = tanh(A0 @ W0a + ab0) -> sH0 bf16 ----
    {
        float b0v[4];
        #pragma unroll
        for (int j = 0; j < 4; ++j) b0v[j] = ab0[j * 16 + lrow];
        bhalf8 a[4];
        #pragma unroll
        for (int mtl = 0; mtl < 4; ++mtl)
            a[mtl] = *(const bhalf8*)&sA0[(wave * 64 + mtl * 16 + lrow) * 32 + lkg * 8];
        #pragma unroll
        for (int j = 0; j < 4; ++j) {
            bhalf8 bf = *(const bhalf8*)(W0a + (j * 16 + lrow) * 32 + lkg * 8);
            #pragma unroll
            for (int mtl = 0; mtl < 4; ++mtl) {
                floatx4 c = {0.f, 0.f, 0.f, 0.f};
                c = __builtin_amdgcn_mfma_f32_16x16x32_bf16(a[mtl], bf, c, 0, 0, 0);
                #pragma unroll
                for (int q = 0; q < 4; ++q) {
                    int row = wave * 64 + mtl * 16 + lkg * 4 + q;
                    sH0[row * AH0S + j * 16 + lrow] = f2b(fast_tanh(c[q] + b0v[j]));
                }
            }
        }
    }
    __syncthreads();

    // ---- L2 + logit: s = sum_i tanh(h1)*aw2[i] in C-space ----
    {
        float b1v[4], w2v[4];
        #pragma unroll
        for (int j = 0; j < 4; ++j) { b1v[j] = ab1[j * 16 + lrow]; w2v[j] = aw2[j * 16 + lrow]; }
        bhalf8 a0[4], a1[4];
        #pragma unroll
        for (int mtl = 0; mtl < 4; ++mtl) {
            int base = (wave * 64 + mtl * 16 + lrow) * AH0S;
            a0[mtl] = *(const bhalf8*)&sH0[base + lkg * 8];
            a1[mtl] = *(const bhalf8*)&sH0[base + 32 + lkg * 8];
        }
        float s[4][4];
        #pragma unroll
        for (int mtl = 0; mtl < 4; ++mtl)
            #pragma unroll
            for (int q = 0; q < 4; ++q) s[mtl][q] = 0.0f;
        #pragma unroll
        for (int j = 0; j < 4; ++j) {
            bhalf8 bf0 = *(const bhalf8*)(W1a + (j * 16 + lrow) * 64 + lkg * 8);
            bhalf8 bf1 = *(const bhalf8*)(W1a + (j * 16 + lrow) * 64 + 32 + lkg * 8);
            #pragma unroll
            for (int mtl = 0; mtl < 4; ++mtl) {
                floatx4 c = {0.f, 0.f, 0.f, 0.f};
                c = __builtin_amdgcn_mfma_f32_16x16x32_bf16(a0[mtl], bf0, c, 0, 0, 0);
                c = __builtin_amdgcn_mfma_f32_16x16x32_bf16(a1[mtl], bf1, c, 0, 0, 0);
                #pragma unroll
                for (int q = 0; q < 4; ++q)
                    s[mtl][q] += fast_tanh(c[q] + b1v[j]) * w2v[j];
            }
        }
        #pragma unroll
        for (int mask = 1; mask <= 8; mask <<= 1)
            #pragma unroll
            for (int mtl = 0; mtl < 4; ++mtl)
                #pragma unroll
                for (int q = 0; q < 4; ++q)
                    s[mtl][q] += __shfl_xor(s[mtl][q], mask, 64);
        if (lrow == 0) {
            #pragma unroll
            for (int mtl = 0; mtl < 4; ++mtl)
                #pragma unroll
                for (int q = 0; q < 4; ++q)
                    sLG[wave * 64 + mtl * 16 + lkg * 4 + q] = s[mtl][q];
        }
    }
    __syncthreads();

    // ---- softmax over p + coeff = exp(-attn . sigma) ----
    {
        const int p = tid;
        const float ml = (sPL[p] > 0.0f) ? (sLG[p] + ab2[0]) : -1e30f;
        const int wid = wave;
        float mv = ml;
        for (int o = 32; o > 0; o >>= 1) mv = fmaxf(mv, __shfl_xor(mv, o, 64));
        if (lane == 0) s_red[wid] = mv;
        __syncthreads();
        mv = fmaxf(s_red[0], s_red[1]);

        const float ew = __expf(ml - mv);
        float sv = ew;
        for (int o = 32; o > 0; o >>= 1) sv += __shfl_xor(sv, o, 64);
        if (lane == 0) s_red[2 + wid] = sv;
        __syncthreads();
        sv = s_red[2] + s_red[3];
        const float attn = ew / sv;

        float s0 = attn * sigma[(b * PP + p) * 2 + 0];
        float s1 = attn * sigma[(b * PP + p) * 2 + 1];
        for (int o = 32; o > 0; o >>= 1) { s0 += __shfl_xor(s0, o, 64); s1 += __shfl_xor(s1, o, 64); }
        if (lane == 0) { s_red[4 + wid] = s0; s_red[6 + wid] = s1; }
        __syncthreads();
        if (tid == 0) {
            float c0 = s_red[4] + s_red[5];
            float c1 = s_red[6] + s_red[7];
            int o = ((b * NN + n) * KK1 + k) * CC;
            coeff[o + 0] = __expf(-c0);
            coeff[o + 1] = __expf(-c1);
        }
    }
}

// ---------------------------------------------------------------------------
// Kernel B: MFMA transport, B-fragments hoisted (loaded once per wave).
// ---------------------------------------------------------------------------
#define HS   264
#define GTS  48
#define AS2S 136
#define V2S  32
#define ASS  32

#define U_H0A  0
#define U_GTS  0
#define F_GV   3072
#define F_NEWV 3328
#define U_A2S  7168
#define U_A3   7680
#define U_H1A  12672
#define U_AS2  12672
#define U_V2T  19200
#define U_A0   25344
#define U_AS   25344
#define F_RED  13440
#define F_BBW  13448

__global__ __launch_bounds__(256, 2) void transport_kernel(
    const float* __restrict__ phase, const float* __restrict__ bcoord,
    const float* __restrict__ boundary, const float* __restrict__ bweights,
    const float* __restrict__ velc, const float* __restrict__ vweights,
    const float* __restrict__ scat, const float* __restrict__ selfscat,
    const float* __restrict__ coeff,
    const ushort_t* __restrict__ W0t, const ushort_t* __restrict__ W1t,
    const ushort_t* __restrict__ W2t, const ushort_t* __restrict__ S0t,
    const ushort_t* __restrict__ S1t,
    const float* __restrict__ tb0, const float* __restrict__ tb1,
    const float* __restrict__ tb2, const float* __restrict__ sb0,
    const float* __restrict__ sb1, const float* __restrict__ outw,
    float* __restrict__ out)
{
    __shared__ __align__(16) ushort_t smem[26912];
    float* smf = (float*)smem;

    const int tid = threadIdx.x;
    const int wave = tid >> 6;
    const int lane = tid & 63;
    const int lrow = lane & 15;
    const int lkg  = lane >> 4;

    const int blk = blockIdx.x;
    const int b  = blk >> 10;
    const int n  = (blk >> 5) & 31;
    const int mg = blk & 31;
    const int m0 = mg * 2;

    if (tid < 2)
        smf[F_BBW + tid] = boundary[b * MM + m0 + tid] * bweights[b * MM + m0 + tid];

    // ---- build A0 ----
    for (int idx = tid; idx < 48 * 32; idx += 256) {
        int r = idx >> 5, c = idx & 31;
        float val = 0.0f;
        if (r < 34 && c < 10) {
            int ml = (r >= 17);
            int k = r - ml * 17;
            int m = m0 + ml;
            if (c < 2)      val = phase[(b * NN + n) * 4 + c];
            else if (c < 4) val = (k == 0) ? phase[(b * NN + n) * 4 + c]
                                           : velc[(b * KK + k - 1) * 2 + (c - 2)];
            else if (c < 8) val = bcoord[(b * MM + m) * 4 + (c - 4)];
            else            val = coeff[((b * NN + n) * KK1 + k) * CC + (c - 8)];
        }
        smem[U_A0 + idx] = f2b(val);
    }
    __syncthreads();

    // ---- L0 ----
    {
        float b0v[4];
        #pragma unroll
        for (int j = 0; j < 4; ++j) b0v[j] = tb0[(4 * wave + j) * 16 + lrow];
        bhalf8 a[3];
        #pragma unroll
        for (int mt = 0; mt < 3; ++mt)
            a[mt] = *(const bhalf8*)&smem[U_A0 + (mt * 16 + lrow) * 32 + lkg * 8];
        #pragma unroll
        for (int j = 0; j < 4; ++j) {
            int nt = 4 * wave + j;
            bhalf8 bf = *(const bhalf8*)(W0t + (nt * 16 + lrow) * 32 + lkg * 8);
            #pragma unroll
            for (int mt = 0; mt < 3; ++mt) {
                floatx4 c = {0.f, 0.f, 0.f, 0.f};
                c = __builtin_amdgcn_mfma_f32_16x16x32_bf16(a[mt], bf, c, 0, 0, 0);
                #pragma unroll
                for (int q = 0; q < 4; ++q) {
                    int row = mt * 16 + lkg * 4 + q;
                    smem[U_H0A + row * HS + nt * 16 + lrow] = f2b(fast_tanh(c[q] + b0v[j]));
                }
            }
        }
    }
    __syncthreads();

    // ---- A_s build ----
    for (int idx = tid; idx < 17 * 32; idx += 256) {
        int i = idx >> 5, c = idx & 31;
        float val = 0.0f;
        if (c < 16) {
            float vw = vweights[b * KK + c];
            val = (i < 16) ? (1.0f - selfscat[(b * KK + i) * KK + c]) * vw
                           : (1.0f - scat[(b * NN + n) * KK + c]) * vw;
        }
        smem[U_AS + i * ASS + c] = f2b(val);
    }
    // ---- L1: A-frags in regs, each B-frag loaded once ----
    {
        float b1v[4];
        #pragma unroll
        for (int j = 0; j < 4; ++j) b1v[j] = tb1[(4 * wave + j) * 16 + lrow];
        bhalf8 a[3][8];
        #pragma unroll
        for (int mt = 0; mt < 3; ++mt)
            #pragma unroll
            for (int ks = 0; ks < 8; ++ks)
                a[mt][ks] = *(const bhalf8*)&smem[U_H0A + (mt * 16 + lrow) * HS + ks * 32 + lkg * 8];
        #pragma unroll
        for (int j = 0; j < 4; ++j) {
            int nt = 4 * wave + j;
            const ushort_t* bp = W1t + (nt * 16 + lrow) * 256 + lkg * 8;
            floatx4 c[3];
            #pragma unroll
            for (int mt = 0; mt < 3; ++mt) c[mt] = (floatx4){0.f, 0.f, 0.f, 0.f};
            #pragma unroll
            for (int ks = 0; ks < 8; ++ks) {
                bhalf8 bf = *(const bhalf8*)(bp + ks * 32);
                #pragma unroll
                for (int mt = 0; mt < 3; ++mt)
                    c[mt] = __builtin_amdgcn_mfma_f32_16x16x32_bf16(a[mt][ks], bf, c[mt], 0, 0, 0);
            }
            #pragma unroll
            for (int mt = 0; mt < 3; ++mt)
                #pragma unroll
                for (int q = 0; q < 4; ++q) {
                    int row = mt * 16 + lkg * 4 + q;
                    smem[U_H1A + row * HS + nt * 16 + lrow] = f2b(fast_tanh(c[mt][q] + b1v[j]));
                }
        }
    }
    __syncthreads();

    // ---- L2 prep ----
    for (int idx = tid; idx < 128 * 16; idx += 256) {
        int w = idx >> 4, r = 32 + (idx & 15);
        smem[U_GTS + w * GTS + r] = 0;
    }
    for (int idx = tid; idx < 16 * 32; idx += 256) {
        int r = idx >> 5, c = idx & 31;
        smem[U_A2S + idx] = ((c >> 4) == r) ? smem[U_AS + 16 * ASS + (c & 15)] : (ushort_t)0;
    }
    // ---- L2: g = exp(tanh(h1A@W2t+tb2)) ----
    {
        float b2v[2];
        #pragma unroll
        for (int j = 0; j < 2; ++j) b2v[j] = tb2[(2 * wave + j) * 16 + lrow];
        bhalf8 a[3][8];
        #pragma unroll
        for (int mt = 0; mt < 3; ++mt)
            #pragma unroll
            for (int ks = 0; ks < 8; ++ks)
                a[mt][ks] = *(const bhalf8*)&smem[U_H1A + (mt * 16 + lrow) * HS + ks * 32 + lkg * 8];
        #pragma unroll
        for (int j = 0; j < 2; ++j) {
            int nt = 2 * wave + j;
            const ushort_t* bp = W2t + (nt * 16 + lrow) * 256 + lkg * 8;
            floatx4 c[3];
            #pragma unroll
            for (int mt = 0; mt < 3; ++mt) c[mt] = (floatx4){0.f, 0.f, 0.f, 0.f};
            #pragma unroll
            for (int ks = 0; ks < 8; ++ks) {
                bhalf8 bf = *(const bhalf8*)(bp + ks * 32);
                #pragma unroll
                for (int mt = 0; mt < 3; ++mt)
                    c[mt] = __builtin_amdgcn_mfma_f32_16x16x32_bf16(a[mt][ks], bf, c[mt], 0, 0, 0);
            }
            #pragma unroll
            for (int mt = 0; mt < 3; ++mt)
                #pragma unroll
                for (int q = 0; q < 4; ++q) {
                    int row = mt * 16 + lkg * 4 + q;
                    if (row < 34) {
                        int ml = (row >= 17);
                        int k = row - ml * 17;
                        int col = nt * 16 + lrow;
                        float g = __expf(fast_tanh(c[mt][q] + b2v[j]));
                        if (k == 0) smf[F_GV + ml * 128 + col] = g;
                        else        smem[U_GTS + col * GTS + ml * 16 + (k - 1)] = f2b(g);
                    }
                }
        }
    }
    __syncthreads();

    // ---- resvs ----
    {
        bhalf8 a0 = *(const bhalf8*)&smem[U_AS + lrow * ASS + lkg * 8];
        bhalf8 a1 = *(const bhalf8*)&smem[U_AS + (16 + lrow) * ASS + lkg * 8];
        for (int m = 0; m < 2; ++m) {
            #pragma unroll
            for (int j = 0; j < 2; ++j) {
                int nt = 2 * wave + j;
                bhalf8 bf = *(const bhalf8*)&smem[U_GTS + (nt * 16 + lrow) * GTS + m * 16 + lkg * 8];
                #pragma unroll
                for (int mt = 0; mt < 2; ++mt) {
                    floatx4 c = {0.f, 0.f, 0.f, 0.f};
                    c = __builtin_amdgcn_mfma_f32_16x16x32_bf16(mt ? a1 : a0, bf, c, 0, 0, 0);
                    #pragma unroll
                    for (int q = 0; q < 4; ++q) {
                        int ic = mt * 16 + lkg * 4 + q;
                        if (ic < 17) {
                            int r2 = (ic == 16) ? m * 17 : m * 17 + 1 + ic;
                            smem[U_AS2 + r2 * AS2S + nt * 16 + lrow] = f2b(c[q]);
                        }
                    }
                }
            }
        }
    }
    __syncthreads();

    // ---- sw0 ----
    {
        float s0v[2];
        #pragma unroll
        for (int j = 0; j < 2; ++j) s0v[j] = sb0[(2 * wave + j) * 16 + lrow];
        bhalf8 a[3][4];
        #pragma unroll
        for (int mt = 0; mt < 3; ++mt)
            #pragma unroll
            for (int ks = 0; ks < 4; ++ks)
                a[mt][ks] = *(const bhalf8*)&smem[U_AS2 + (mt * 16 + lrow) * AS2S + ks * 32 + lkg * 8];
        #pragma unroll
        for (int j = 0; j < 2; ++j) {
            int nt = 2 * wave + j;
            const ushort_t* bp = S0t + (nt * 16 + lrow) * 128 + lkg * 8;
            floatx4 c[3];
            #pragma unroll
            for (int mt = 0; mt < 3; ++mt) c[mt] = (floatx4){0.f, 0.f, 0.f, 0.f};
            #pragma unroll
            for (int ks = 0; ks < 4; ++ks) {
                bhalf8 bf = *(const bhalf8*)(bp + ks * 32);
                #pragma unroll
                for (int mt = 0; mt < 3; ++mt)
                    c[mt] = __builtin_amdgcn_mfma_f32_16x16x32_bf16(a[mt][ks], bf, c[mt], 0, 0, 0);
            }
            #pragma unroll
            for (int mt = 0; mt < 3; ++mt)
                #pragma unroll
                for (int q = 0; q < 4; ++q) {
                    int r2 = mt * 16 + lkg * 4 + q;
                    if (r2 < 34) {
                        int m = (r2 >= 17);
                        int i2 = r2 - m * 17;
                        int col = nt * 16 + lrow;
                        float val = fast_tanh(c[mt][q] + s0v[j]);
                        if (i2 == 0) {
                            smf[F_NEWV + m * 128 + col] = smf[F_GV + m * 128 + col] + val;
                        } else {
                            int j2 = i2 - 1;
                            smem[U_V2T + col * V2S + m * 16 + j2] =
                                f2b(b2f(smem[U_GTS + col * GTS + m * 16 + j2]) + val);
                        }
                    }
                }
        }
    }
    __syncthreads();

    // ---- resv2 ----
    {
        bhalf8 a = *(const bhalf8*)&smem[U_A2S + lrow * 32 + lkg * 8];
        #pragma unroll
        for (int j = 0; j < 2; ++j) {
            int nt = 2 * wave + j;
            bhalf8 bf = *(const bhalf8*)&smem[U_V2T + (nt * 16 + lrow) * V2S + lkg * 8];
            floatx4 c = {0.f, 0.f, 0.f, 0.f};
            c = __builtin_amdgcn_mfma_f32_16x16x32_bf16(a, bf, c, 0, 0, 0);
            #pragma unroll
            for (int q = 0; q < 4; ++q) {
                int r = lkg * 4 + q;
                smem[U_A3 + r * AS2S + nt * 16 + lrow] = f2b(c[q]);
            }
        }
    }
    __syncthreads();

    // ---- green + output ----
    float acc = 0.0f;
    {
        float s1v[2], owv[2];
        #pragma unroll
        for (int j = 0; j < 2; ++j) {
            s1v[j] = sb1[(2 * wave + j) * 16 + lrow];
            owv[j] = outw[(2 * wave + j) * 16 + lrow];
        }
        bhalf8 a[4];
        #pragma unroll
        for (int ks = 0; ks < 4; ++ks)
            a[ks] = *(const bhalf8*)&smem[U_A3 + lrow * AS2S + ks * 32 + lkg * 8];
        #pragma unroll
        for (int j = 0; j < 2; ++j) {
            int nt = 2 * wave + j;
            const ushort_t* bp = S1t + (nt * 16 + lrow) * 128 + lkg * 8;
            floatx4 c = {0.f, 0.f, 0.f, 0.f};
            #pragma unroll
            for (int ks = 0; ks < 4; ++ks) {
                bhalf8 bf = *(const bhalf8*)(bp + ks * 32);
                c = __builtin_amdgcn_mfma_f32_16x16x32_bf16(a[ks], bf, c, 0, 0, 0);
            }
            #pragma unroll
            for (int q = 0; q < 4; ++q) {
                int r = lkg * 4 + q;
                if (r < 2) {
                    int col = nt * 16 + lrow;
                    float green = smf[F_NEWV + r * 128 + col] + fast_tanh(c[q] + s1v[j]);
                    acc += green * owv[j] * smf[F_BBW + r];
                }
            }
        }
    }
    for (int o = 32; o > 0; o >>= 1) acc += __shfl_xor(acc, o, 64);
    if (lane == 0) smf[F_RED + wave] = acc;
    __syncthreads();
    if (tid == 0) {
        float tot = smf[F_RED + 0] + smf[F_RED + 1] + smf[F_RED + 2] + smf[F_RED + 3];
        atomicAdd(&out[b * NN + n], tot);
    }
}

extern "C" void kernel_launch(void* const* d_in, const int* in_sizes, int n_in,
                              void* d_out, int out_size, void* d_ws, size_t ws_size,
                              hipStream_t stream) {
    const float* phase    = (const float*)d_in[0];
    const float* bcoord   = (const float*)d_in[1];
    const float* boundary = (const float*)d_in[2];
    const float* bweights = (const float*)d_in[3];
    const float* posc     = (const float*)d_in[4];
    const float* sigma    = (const float*)d_in[5];
    const float* velc     = (const float*)d_in[6];
    const float* vweights = (const float*)d_in[7];
    const float* scat     = (const float*)d_in[8];
    const float* selfscat = (const float*)d_in[9];
    const float* aw0 = (const float*)d_in[10];
    const float* ab0 = (const float*)d_in[11];
    const float* aw1 = (const float*)d_in[12];
    const float* ab1 = (const float*)d_in[13];
    const float* aw2 = (const float*)d_in[14];
    const float* ab2 = (const float*)d_in[15];
    const float* tw0 = (const float*)d_in[16];
    const float* tb0 = (const float*)d_in[17];
    const float* tw1 = (const float*)d_in[18];
    const float* tb1 = (const float*)d_in[19];
    const float* tw2 = (const float*)d_in[20];
    const float* tb2 = (const float*)d_in[21];
    const float* sw0 = (const float*)d_in[22];
    const float* sb0 = (const float*)d_in[23];
    const float* sw1 = (const float*)d_in[24];
    const float* sb1 = (const float*)d_in[25];
    const float* outw = (const float*)d_in[26];

    float* out = (float*)d_out;
    char* ws = (char*)d_ws;
    float* coeff = (float*)ws;                      // 17408 B
    ushort_t* W0t = (ushort_t*)(ws + 17408);        // 16384 B
    ushort_t* W1t = (ushort_t*)(ws + 33792);        // 131072 B
    ushort_t* W2t = (ushort_t*)(ws + 164864);       // 65536 B
    ushort_t* S0t = (ushort_t*)(ws + 230400);       // 32768 B
    ushort_t* S1t = (ushort_t*)(ws + 263168);       // 32768 B
    ushort_t* W0a = (ushort_t*)(ws + 295936);       // 4096 B
    ushort_t* W1a = (ushort_t*)(ws + 300032);       // 8192 B -> 308224 total

    hipMemsetAsync(d_out, 0, (size_t)out_size * sizeof(float), stream);

    prep_kernel<<<568, 256, 0, stream>>>(tw0, tw1, tw2, sw0, sw1, aw0, aw1,
                                         W0t, W1t, W2t, S0t, S1t, W0a, W1a);

    attn_kernel<<<BB * NN * KK1, 128, 0, stream>>>(
        phase, posc, sigma, velc, W0a, W1a, ab0, ab1, aw2, ab2, coeff);

    transport_kernel<<<BB * NN * 32, 256, 0, stream>>>(
        phase, bcoord, boundary, bweights, velc, vweights, scat, selfscat, coeff,
        W0t, W1t, W2t, S0t, S1t, tb0, tb1, tb2, sb0, sb1, outw, out);
}

// Round 5
// 301.222 us; speedup vs baseline: 3.5073x; 1.1105x over previous
//
#include <hip/hip_runtime.h>
#include <hip/hip_bf16.h>

#define BB 4
#define NN 32
#define MM 64
#define KK 16
#define KK1 17
#define PP 128
#define CC 2

typedef unsigned short ushort_t;
typedef unsigned int uint32;
typedef __attribute__((ext_vector_type(8))) short bhalf8;
typedef __attribute__((ext_vector_type(4))) float floatx4;

__device__ __forceinline__ float fast_tanh(float x) {
    float e = __expf(2.0f * x);
    return 1.0f - 2.0f / (e + 1.0f);
}
__device__ __forceinline__ ushort_t f2b(float f) {
    uint32 u = __float_as_uint(f);
    return (ushort_t)((u + 0x8000u) >> 16);  // round-half-up bf16
}
__device__ __forceinline__ float b2f(ushort_t h) {
    return __uint_as_float(((uint32)h) << 16);
}

// ---------------------------------------------------------------------------
// Prep: all weights -> bf16 B-operand layouts (W^T, k-contiguous) in ws
// ---------------------------------------------------------------------------
__global__ void prep_kernel(const float* __restrict__ tw0, const float* __restrict__ tw1,
                            const float* __restrict__ tw2, const float* __restrict__ sw0,
                            const float* __restrict__ sw1, const float* __restrict__ aw0,
                            const float* __restrict__ aw1,
                            ushort_t* __restrict__ W0t, ushort_t* __restrict__ W1t,
                            ushort_t* __restrict__ W2t, ushort_t* __restrict__ S0t,
                            ushort_t* __restrict__ S1t, ushort_t* __restrict__ W0a,
                            ushort_t* __restrict__ W1a) {
    int i = blockIdx.x * 256 + threadIdx.x;
    if (i < 8192) {
        int nn = i >> 5, k = i & 31;
        W0t[i] = (k < 10) ? f2b(tw0[k * 256 + nn]) : (ushort_t)0;
    } else if (i < 73728) {
        int j = i - 8192; int nn = j >> 8, k = j & 255;
        W1t[j] = f2b(tw1[k * 256 + nn]);
    } else if (i < 106496) {
        int j = i - 73728; int nn = j >> 8, k = j & 255;
        W2t[j] = f2b(tw2[k * 128 + nn]);
    } else if (i < 122880) {
        S0t[i - 106496] = f2b(sw0[i - 106496]);
    } else if (i < 139264) {
        S1t[i - 122880] = f2b(sw1[i - 122880]);
    } else if (i < 141312) {
        int j = i - 139264; int nn = j >> 5, k = j & 31;
        W0a[j] = (k < 6) ? f2b(aw0[k * 64 + nn]) : (ushort_t)0;
    } else if (i < 145408) {
        int j = i - 141312; int nn = j >> 6, k = j & 63;
        W1a[j] = f2b(aw1[k * 64 + nn]);
    }
}

// ---------------------------------------------------------------------------
// Kernel A (MFMA): block per (b,n,k); 128 thr = 2 waves; M=128 p-rows.
// ---------------------------------------------------------------------------
#define AH0S 72   // h0 LDS stride (64+8)

__global__ __launch_bounds__(128) void attn_kernel(
    const float* __restrict__ phase, const float* __restrict__ posc,
    const float* __restrict__ sigma, const float* __restrict__ velc,
    const ushort_t* __restrict__ W0a, const ushort_t* __restrict__ W1a,
    const float* __restrict__ ab0, const float* __restrict__ ab1,
    const float* __restrict__ aw2, const float* __restrict__ ab2,
    float* __restrict__ coeff)
{
    __shared__ __align__(16) ushort_t sA0[128 * 32];
    __shared__ __align__(16) ushort_t sH0[128 * AH0S];
    __shared__ float sPL[128];
    __shared__ float sLG[128];
    __shared__ float s_red[8];

    const int tid = threadIdx.x;
    const int wave = tid >> 6;
    const int lane = tid & 63;
    const int lrow = lane & 15;
    const int lkg  = lane >> 4;

    const int blk = blockIdx.x;
    const int b = blk / (NN * KK1);
    const int rem = blk % (NN * KK1);
    const int n = rem / KK1;
    const int k = rem % KK1;

    {
        const int p = tid;
        const float x0 = phase[(b * NN + n) * 4 + 0];
        const float x1 = phase[(b * NN + n) * 4 + 1];
        float va0, va1;
        if (k == 0) { va0 = phase[(b * NN + n) * 4 + 2]; va1 = phase[(b * NN + n) * 4 + 3]; }
        else { va0 = velc[(b * KK + (k - 1)) * 2 + 0]; va1 = velc[(b * KK + (k - 1)) * 2 + 1]; }
        const float inv = rsqrtf(va0 * va0 + va1 * va1 + 1e-16f);
        const float ag0 = va0 * inv, ag1 = va1 * inv;
        const float px = posc[(b * PP + p) * 2 + 0];
        const float py = posc[(b * PP + p) * 2 + 1];
        const float r0 = x0 - px, r1 = x1 - py;
        const float rd = sqrtf(r0 * r0 + r1 * r1 + 1e-16f);
        const float pl = r0 * ag0 + r1 * ag1;
        const float al = pl / (rd + 1e-8f);
        sPL[p] = pl;
        float feat[6] = {x0, x1, va0, va1, al, pl};
        #pragma unroll
        for (int c = 0; c < 6; ++c) sA0[p * 32 + c] = f2b(feat[c]);
        #pragma unroll
        for (int c = 6; c < 32; ++c) sA0[p * 32 + c] = 0;
    }
    __syncthreads();

    // ---- L1: h0 = tanh(A0 @ W0a + ab0) ----
    {
        float b0v[4];
        #pragma unroll
        for (int j = 0; j < 4; ++j) b0v[j] = ab0[j * 16 + lrow];
        bhalf8 a[4];
        #pragma unroll
        for (int mtl = 0; mtl < 4; ++mtl)
            a[mtl] = *(const bhalf8*)&sA0[(wave * 64 + mtl * 16 + lrow) * 32 + lkg * 8];
        #pragma unroll
        for (int j = 0; j < 4; ++j) {
            bhalf8 bf = *(const bhalf8*)(W0a + (j * 16 + lrow) * 32 + lkg * 8);
            #pragma unroll
            for (int mtl = 0; mtl < 4; ++mtl) {
                floatx4 c = {0.f, 0.f, 0.f, 0.f};
                c = __builtin_amdgcn_mfma_f32_16x16x32_bf16(a[mtl], bf, c, 0, 0, 0);
                #pragma unroll
                for (int q = 0; q < 4; ++q) {
                    int row = wave * 64 + mtl * 16 + lkg * 4 + q;
                    sH0[row * AH0S + j * 16 + lrow] = f2b(fast_tanh(c[q] + b0v[j]));
                }
            }
        }
    }
    __syncthreads();

    // ---- L2 + logit ----
    {
        float b1v[4], w2v[4];
        #pragma unroll
        for (int j = 0; j < 4; ++j) { b1v[j] = ab1[j * 16 + lrow]; w2v[j] = aw2[j * 16 + lrow]; }
        bhalf8 a0[4], a1[4];
        #pragma unroll
        for (int mtl = 0; mtl < 4; ++mtl) {
            int base = (wave * 64 + mtl * 16 + lrow) * AH0S;
            a0[mtl] = *(const bhalf8*)&sH0[base + lkg * 8];
            a1[mtl] = *(const bhalf8*)&sH0[base + 32 + lkg * 8];
        }
        float s[4][4];
        #pragma unroll
        for (int mtl = 0; mtl < 4; ++mtl)
            #pragma unroll
            for (int q = 0; q < 4; ++q) s[mtl][q] = 0.0f;
        #pragma unroll
        for (int j = 0; j < 4; ++j) {
            bhalf8 bf0 = *(const bhalf8*)(W1a + (j * 16 + lrow) * 64 + lkg * 8);
            bhalf8 bf1 = *(const bhalf8*)(W1a + (j * 16 + lrow) * 64 + 32 + lkg * 8);
            #pragma unroll
            for (int mtl = 0; mtl < 4; ++mtl) {
                floatx4 c = {0.f, 0.f, 0.f, 0.f};
                c = __builtin_amdgcn_mfma_f32_16x16x32_bf16(a0[mtl], bf0, c, 0, 0, 0);
                c = __builtin_amdgcn_mfma_f32_16x16x32_bf16(a1[mtl], bf1, c, 0, 0, 0);
                #pragma unroll
                for (int q = 0; q < 4; ++q)
                    s[mtl][q] += fast_tanh(c[q] + b1v[j]) * w2v[j];
            }
        }
        #pragma unroll
        for (int mask = 1; mask <= 8; mask <<= 1)
            #pragma unroll
            for (int mtl = 0; mtl < 4; ++mtl)
                #pragma unroll
                for (int q = 0; q < 4; ++q)
                    s[mtl][q] += __shfl_xor(s[mtl][q], mask, 64);
        if (lrow == 0) {
            #pragma unroll
            for (int mtl = 0; mtl < 4; ++mtl)
                #pragma unroll
                for (int q = 0; q < 4; ++q)
                    sLG[wave * 64 + mtl * 16 + lkg * 4 + q] = s[mtl][q];
        }
    }
    __syncthreads();

    // ---- softmax + coeff ----
    {
        const int p = tid;
        const float ml = (sPL[p] > 0.0f) ? (sLG[p] + ab2[0]) : -1e30f;
        const int wid = wave;
        float mv = ml;
        for (int o = 32; o > 0; o >>= 1) mv = fmaxf(mv, __shfl_xor(mv, o, 64));
        if (lane == 0) s_red[wid] = mv;
        __syncthreads();
        mv = fmaxf(s_red[0], s_red[1]);

        const float ew = __expf(ml - mv);
        float sv = ew;
        for (int o = 32; o > 0; o >>= 1) sv += __shfl_xor(sv, o, 64);
        if (lane == 0) s_red[2 + wid] = sv;
        __syncthreads();
        sv = s_red[2] + s_red[3];
        const float attn = ew / sv;

        float s0 = attn * sigma[(b * PP + p) * 2 + 0];
        float s1 = attn * sigma[(b * PP + p) * 2 + 1];
        for (int o = 32; o > 0; o >>= 1) { s0 += __shfl_xor(s0, o, 64); s1 += __shfl_xor(s1, o, 64); }
        if (lane == 0) { s_red[4 + wid] = s0; s_red[6 + wid] = s1; }
        __syncthreads();
        if (tid == 0) {
            float c0 = s_red[4] + s_red[5];
            float c1 = s_red[6] + s_red[7];
            int o = ((b * NN + n) * KK1 + k) * CC;
            coeff[o + 0] = __expf(-c0);
            coeff[o + 1] = __expf(-c1);
        }
    }
}

// ---------------------------------------------------------------------------
// Kernel B: MFMA transport. 47.3 KB LDS (3 blocks/CU). H0A/H1A store only
// rows<34 (writes guarded); MFMA tail-row reads hit successor regions as
// harmless garbage (D rows >=34 are discarded).
// Region X [0,8976):      H0A(34x264) -> GTS(128x56)+GV+NEWV+A2S
// Region Y [8976,17952):  H1A(34x264) -> AS2(34x136)+A3(16x136)
// Region Z [17952,23616): A0(48x32) -> AS(17x32) -> V2T(128x40)
// BBW/RED [23616,23628) — never overlapped.
// ---------------------------------------------------------------------------
#define HS   264
#define GTS  56
#define AS2S 136
#define V2S  40
#define ASS  32

#define U_H0A  0
#define U_GTS  0
#define F_GV   3584   // u 7168..7680
#define F_NEWV 3840   // u 7680..8192
#define U_A2S  8192   // u 8192..8704
#define U_H1A  8976
#define U_AS2  8976   // u 8976..13600
#define U_A3   13600  // u 13600..15776
#define U_A0   17952  // u 17952..19488
#define U_AS   17952  // u 17952..18496
#define U_V2T  18496  // u 18496..23616
#define F_BBW  11808  // u 23616..23620
#define F_RED  11810  // u 23620..23628

__global__ __launch_bounds__(256, 3) void transport_kernel(
    const float* __restrict__ phase, const float* __restrict__ bcoord,
    const float* __restrict__ boundary, const float* __restrict__ bweights,
    const float* __restrict__ velc, const float* __restrict__ vweights,
    const float* __restrict__ scat, const float* __restrict__ selfscat,
    const float* __restrict__ coeff,
    const ushort_t* __restrict__ W0t, const ushort_t* __restrict__ W1t,
    const ushort_t* __restrict__ W2t, const ushort_t* __restrict__ S0t,
    const ushort_t* __restrict__ S1t,
    const float* __restrict__ tb0, const float* __restrict__ tb1,
    const float* __restrict__ tb2, const float* __restrict__ sb0,
    const float* __restrict__ sb1, const float* __restrict__ outw,
    float* __restrict__ out)
{
    __shared__ __align__(16) ushort_t smem[23640];
    float* smf = (float*)smem;

    const int tid = threadIdx.x;
    const int wave = tid >> 6;
    const int lane = tid & 63;
    const int lrow = lane & 15;
    const int lkg  = lane >> 4;

    const int blk = blockIdx.x;
    const int b  = blk >> 10;
    const int n  = (blk >> 5) & 31;
    const int mg = blk & 31;
    const int m0 = mg * 2;

    if (tid < 2)
        smf[F_BBW + tid] = boundary[b * MM + m0 + tid] * bweights[b * MM + m0 + tid];

    // ---- build A0 (Z region) ----
    for (int idx = tid; idx < 48 * 32; idx += 256) {
        int r = idx >> 5, c = idx & 31;
        float val = 0.0f;
        if (r < 34 && c < 10) {
            int ml = (r >= 17);
            int k = r - ml * 17;
            int m = m0 + ml;
            if (c < 2)      val = phase[(b * NN + n) * 4 + c];
            else if (c < 4) val = (k == 0) ? phase[(b * NN + n) * 4 + c]
                                           : velc[(b * KK + k - 1) * 2 + (c - 2)];
            else if (c < 8) val = bcoord[(b * MM + m) * 4 + (c - 4)];
            else            val = coeff[((b * NN + n) * KK1 + k) * CC + (c - 8)];
        }
        smem[U_A0 + idx] = f2b(val);
    }
    __syncthreads();

    // ---- L0: read A0 (Z), write H0A (X, rows<34) ----
    {
        float b0v[4];
        #pragma unroll
        for (int j = 0; j < 4; ++j) b0v[j] = tb0[(4 * wave + j) * 16 + lrow];
        bhalf8 a[3];
        #pragma unroll
        for (int mt = 0; mt < 3; ++mt)
            a[mt] = *(const bhalf8*)&smem[U_A0 + (mt * 16 + lrow) * 32 + lkg * 8];
        #pragma unroll
        for (int j = 0; j < 4; ++j) {
            int nt = 4 * wave + j;
            bhalf8 bf = *(const bhalf8*)(W0t + (nt * 16 + lrow) * 32 + lkg * 8);
            #pragma unroll
            for (int mt = 0; mt < 3; ++mt) {
                floatx4 c = {0.f, 0.f, 0.f, 0.f};
                c = __builtin_amdgcn_mfma_f32_16x16x32_bf16(a[mt], bf, c, 0, 0, 0);
                #pragma unroll
                for (int q = 0; q < 4; ++q) {
                    int row = mt * 16 + lkg * 4 + q;
                    if (row < 34)
                        smem[U_H0A + row * HS + nt * 16 + lrow] = f2b(fast_tanh(c[q] + b0v[j]));
                }
            }
        }
    }
    __syncthreads();

    // ---- AS build (Z, over dead A0) — same interval as L1 ----
    for (int idx = tid; idx < 17 * 32; idx += 256) {
        int i = idx >> 5, c = idx & 31;
        float val = 0.0f;
        if (c < 16) {
            float vw = vweights[b * KK + c];
            val = (i < 16) ? (1.0f - selfscat[(b * KK + i) * KK + c]) * vw
                           : (1.0f - scat[(b * NN + n) * KK + c]) * vw;
        }
        smem[U_AS + i * ASS + c] = f2b(val);
    }
    // ---- L1: read H0A (X; tail rows garbage-OK), write H1A (Y, rows<34) ----
    {
        float b1v[4];
        #pragma unroll
        for (int j = 0; j < 4; ++j) b1v[j] = tb1[(4 * wave + j) * 16 + lrow];
        bhalf8 a[3][8];
        #pragma unroll
        for (int mt = 0; mt < 3; ++mt)
            #pragma unroll
            for (int ks = 0; ks < 8; ++ks)
                a[mt][ks] = *(const bhalf8*)&smem[U_H0A + (mt * 16 + lrow) * HS + ks * 32 + lkg * 8];
        #pragma unroll
        for (int j = 0; j < 4; ++j) {
            int nt = 4 * wave + j;
            const ushort_t* bp = W1t + (nt * 16 + lrow) * 256 + lkg * 8;
            floatx4 c[3];
            #pragma unroll
            for (int mt = 0; mt < 3; ++mt) c[mt] = (floatx4){0.f, 0.f, 0.f, 0.f};
            #pragma unroll
            for (int ks = 0; ks < 8; ++ks) {
                bhalf8 bf = *(const bhalf8*)(bp + ks * 32);
                #pragma unroll
                for (int mt = 0; mt < 3; ++mt)
                    c[mt] = __builtin_amdgcn_mfma_f32_16x16x32_bf16(a[mt][ks], bf, c[mt], 0, 0, 0);
            }
            #pragma unroll
            for (int mt = 0; mt < 3; ++mt)
                #pragma unroll
                for (int q = 0; q < 4; ++q) {
                    int row = mt * 16 + lkg * 4 + q;
                    if (row < 34)
                        smem[U_H1A + row * HS + nt * 16 + lrow] = f2b(fast_tanh(c[mt][q] + b1v[j]));
                }
        }
    }
    __syncthreads();

    // ---- L2 prep: zero GTS K-pad rows 32..47; build A2S (X, from AS row 16) ----
    for (int idx = tid; idx < 128 * 16; idx += 256) {
        int w = idx >> 4, r = 32 + (idx & 15);
        smem[U_GTS + w * GTS + r] = 0;
    }
    for (int idx = tid; idx < 16 * 32; idx += 256) {
        int r = idx >> 5, c = idx & 31;
        smem[U_A2S + idx] = ((c >> 4) == r) ? smem[U_AS + 16 * ASS + (c & 15)] : (ushort_t)0;
    }
    // ---- L2: read H1A (Y; tail garbage-OK), write GTS+GV (X) ----
    {
        float b2v[2];
        #pragma unroll
        for (int j = 0; j < 2; ++j) b2v[j] = tb2[(2 * wave + j) * 16 + lrow];
        bhalf8 a[3][8];
        #pragma unroll
        for (int mt = 0; mt < 3; ++mt)
            #pragma unroll
            for (int ks = 0; ks < 8; ++ks)
                a[mt][ks] = *(const bhalf8*)&smem[U_H1A + (mt * 16 + lrow) * HS + ks * 32 + lkg * 8];
        #pragma unroll
        for (int j = 0; j < 2; ++j) {
            int nt = 2 * wave + j;
            const ushort_t* bp = W2t + (nt * 16 + lrow) * 256 + lkg * 8;
            floatx4 c[3];
            #pragma unroll
            for (int mt = 0; mt < 3; ++mt) c[mt] = (floatx4){0.f, 0.f, 0.f, 0.f};
            #pragma unroll
            for (int ks = 0; ks < 8; ++ks) {
                bhalf8 bf = *(const bhalf8*)(bp + ks * 32);
                #pragma unroll
                for (int mt = 0; mt < 3; ++mt)
                    c[mt] = __builtin_amdgcn_mfma_f32_16x16x32_bf16(a[mt][ks], bf, c[mt], 0, 0, 0);
            }
            #pragma unroll
            for (int mt = 0; mt < 3; ++mt)
                #pragma unroll
                for (int q = 0; q < 4; ++q) {
                    int row = mt * 16 + lkg * 4 + q;
                    if (row < 34) {
                        int ml = (row >= 17);
                        int k = row - ml * 17;
                        int col = nt * 16 + lrow;
                        float g = __expf(fast_tanh(c[mt][q] + b2v[j]));
                        if (k == 0) smf[F_GV + ml * 128 + col] = g;
                        else        smem[U_GTS + col * GTS + ml * 16 + (k - 1)] = f2b(g);
                    }
                }
        }
    }
    __syncthreads();

    // ---- resvs: read AS (Z) + GTS (X), write AS2 (Y) ----
    {
        bhalf8 a0 = *(const bhalf8*)&smem[U_AS + lrow * ASS + lkg * 8];
        bhalf8 a1 = *(const bhalf8*)&smem[U_AS + (16 + lrow) * ASS + lkg * 8];
        for (int m = 0; m < 2; ++m) {
            #pragma unroll
            for (int j = 0; j < 2; ++j) {
                int nt = 2 * wave + j;
                bhalf8 bf = *(const bhalf8*)&smem[U_GTS + (nt * 16 + lrow) * GTS + m * 16 + lkg * 8];
                #pragma unroll
                for (int mt = 0; mt < 2; ++mt) {
                    floatx4 c = {0.f, 0.f, 0.f, 0.f};
                    c = __builtin_amdgcn_mfma_f32_16x16x32_bf16(mt ? a1 : a0, bf, c, 0, 0, 0);
                    #pragma unroll
                    for (int q = 0; q < 4; ++q) {
                        int ic = mt * 16 + lkg * 4 + q;
                        if (ic < 17) {
                            int r2 = (ic == 16) ? m * 17 : m * 17 + 1 + ic;
                            smem[U_AS2 + r2 * AS2S + nt * 16 + lrow] = f2b(c[q]);
                        }
                    }
                }
            }
        }
    }
    __syncthreads();

    // ---- sw0: read AS2 (Y; tail garbage-OK) + GTS/GV (X), write NEWV (X) + V2T (Z) ----
    {
        float s0v[2];
        #pragma unroll
        for (int j = 0; j < 2; ++j) s0v[j] = sb0[(2 * wave + j) * 16 + lrow];
        bhalf8 a[3][4];
        #pragma unroll
        for (int mt = 0; mt < 3; ++mt)
            #pragma unroll
            for (int ks = 0; ks < 4; ++ks)
                a[mt][ks] = *(const bhalf8*)&smem[U_AS2 + (mt * 16 + lrow) * AS2S + ks * 32 + lkg * 8];
        #pragma unroll
        for (int j = 0; j < 2; ++j) {
            int nt = 2 * wave + j;
            const ushort_t* bp = S0t + (nt * 16 + lrow) * 128 + lkg * 8;
            floatx4 c[3];
            #pragma unroll
            for (int mt = 0; mt < 3; ++mt) c[mt] = (floatx4){0.f, 0.f, 0.f, 0.f};
            #pragma unroll
            for (int ks = 0; ks < 4; ++ks) {
                bhalf8 bf = *(const bhalf8*)(bp + ks * 32);
                #pragma unroll
                for (int mt = 0; mt < 3; ++mt)
                    c[mt] = __builtin_amdgcn_mfma_f32_16x16x32_bf16(a[mt][ks], bf, c[mt], 0, 0, 0);
            }
            #pragma unroll
            for (int mt = 0; mt < 3; ++mt)
                #pragma unroll
                for (int q = 0; q < 4; ++q) {
                    int r2 = mt * 16 + lkg * 4 + q;
                    if (r2 < 34) {
                        int m = (r2 >= 17);
                        int i2 = r2 - m * 17;
                        int col = nt * 16 + lrow;
                        float val = fast_tanh(c[mt][q] + s0v[j]);
                        if (i2 == 0) {
                            smf[F_NEWV + m * 128 + col] = smf[F_GV + m * 128 + col] + val;
                        } else {
                            int j2 = i2 - 1;
                            smem[U_V2T + col * V2S + m * 16 + j2] =
                                f2b(b2f(smem[U_GTS + col * GTS + m * 16 + j2]) + val);
                        }
                    }
                }
        }
    }
    __syncthreads();

    // ---- resv2: read A2S (X) + V2T (Z), write A3 (Y) ----
    {
        bhalf8 a = *(const bhalf8*)&smem[U_A2S + lrow * 32 + lkg * 8];
        #pragma unroll
        for (int j = 0; j < 2; ++j) {
            int nt = 2 * wave + j;
            bhalf8 bf = *(const bhalf8*)&smem[U_V2T + (nt * 16 + lrow) * V2S + lkg * 8];
            floatx4 c = {0.f, 0.f, 0.f, 0.f};
            c = __builtin_amdgcn_mfma_f32_16x16x32_bf16(a, bf, c, 0, 0, 0);
            #pragma unroll
            for (int q = 0; q < 4; ++q) {
                int r = lkg * 4 + q;
                smem[U_A3 + r * AS2S + nt * 16 + lrow] = f2b(c[q]);
            }
        }
    }
    __syncthreads();

    // ---- green: read A3 (Y) + NEWV (X), dot outw, weight bbw ----
    float acc = 0.0f;
    {
        float s1v[2], owv[2];
        #pragma unroll
        for (int j = 0; j < 2; ++j) {
            s1v[j] = sb1[(2 * wave + j) * 16 + lrow];
            owv[j] = outw[(2 * wave + j) * 16 + lrow];
        }
        bhalf8 a[4];
        #pragma unroll
        for (int ks = 0; ks < 4; ++ks)
            a[ks] = *(const bhalf8*)&smem[U_A3 + lrow * AS2S + ks * 32 + lkg * 8];
        #pragma unroll
        for (int j = 0; j < 2; ++j) {
            int nt = 2 * wave + j;
            const ushort_t* bp = S1t + (nt * 16 + lrow) * 128 + lkg * 8;
            floatx4 c = {0.f, 0.f, 0.f, 0.f};
            #pragma unroll
            for (int ks = 0; ks < 4; ++ks) {
                bhalf8 bf = *(const bhalf8*)(bp + ks * 32);
                c = __builtin_amdgcn_mfma_f32_16x16x32_bf16(a[ks], bf, c, 0, 0, 0);
            }
            #pragma unroll
            for (int q = 0; q < 4; ++q) {
                int r = lkg * 4 + q;
                if (r < 2) {
                    int col = nt * 16 + lrow;
                    float green = smf[F_NEWV + r * 128 + col] + fast_tanh(c[q] + s1v[j]);
                    acc += green * owv[j] * smf[F_BBW + r];
                }
            }
        }
    }
    for (int o = 32; o > 0; o >>= 1) acc += __shfl_xor(acc, o, 64);
    if (lane == 0) smf[F_RED + wave] = acc;
    __syncthreads();
    if (tid == 0) {
        float tot = smf[F_RED + 0] + smf[F_RED + 1] + smf[F_RED + 2] + smf[F_RED + 3];
        atomicAdd(&out[b * NN + n], tot);
    }
}

extern "C" void kernel_launch(void* const* d_in, const int* in_sizes, int n_in,
                              void* d_out, int out_size, void* d_ws, size_t ws_size,
                              hipStream_t stream) {
    const float* phase    = (const float*)d_in[0];
    const float* bcoord   = (const float*)d_in[1];
    const float* boundary = (const float*)d_in[2];
    const float* bweights = (const float*)d_in[3];
    const float* posc     = (const float*)d_in[4];
    const float* sigma    = (const float*)d_in[5];
    const float* velc     = (const float*)d_in[6];
    const float* vweights = (const float*)d_in[7];
    const float* scat     = (const float*)d_in[8];
    const float* selfscat = (const float*)d_in[9];
    const float* aw0 = (const float*)d_in[10];
    const float* ab0 = (const float*)d_in[11];
    const float* aw1 = (const float*)d_in[12];
    const float* ab1 = (const float*)d_in[13];
    const float* aw2 = (const float*)d_in[14];
    const float* ab2 = (const float*)d_in[15];
    const float* tw0 = (const float*)d_in[16];
    const float* tb0 = (const float*)d_in[17];
    const float* tw1 = (const float*)d_in[18];
    const float* tb1 = (const float*)d_in[19];
    const float* tw2 = (const float*)d_in[20];
    const float* tb2 = (const float*)d_in[21];
    const float* sw0 = (const float*)d_in[22];
    const float* sb0 = (const float*)d_in[23];
    const float* sw1 = (const float*)d_in[24];
    const float* sb1 = (const float*)d_in[25];
    const float* outw = (const float*)d_in[26];

    float* out = (float*)d_out;
    char* ws = (char*)d_ws;
    float* coeff = (float*)ws;                      // 17408 B
    ushort_t* W0t = (ushort_t*)(ws + 17408);        // 16384 B
    ushort_t* W1t = (ushort_t*)(ws + 33792);        // 131072 B
    ushort_t* W2t = (ushort_t*)(ws + 164864);       // 65536 B
    ushort_t* S0t = (ushort_t*)(ws + 230400);       // 32768 B
    ushort_t* S1t = (ushort_t*)(ws + 263168);       // 32768 B
    ushort_t* W0a = (ushort_t*)(ws + 295936);       // 4096 B
    ushort_t* W1a = (ushort_t*)(ws + 300032);       // 8192 B -> 308224 total

    hipMemsetAsync(d_out, 0, (size_t)out_size * sizeof(float), stream);

    prep_kernel<<<568, 256, 0, stream>>>(tw0, tw1, tw2, sw0, sw1, aw0, aw1,
                                         W0t, W1t, W2t, S0t, S1t, W0a, W1a);

    attn_kernel<<<BB * NN * KK1, 128, 0, stream>>>(
        phase, posc, sigma, velc, W0a, W1a, ab0, ab1, aw2, ab2, coeff);

    transport_kernel<<<BB * NN * 32, 256, 0, stream>>>(
        phase, bcoord, boundary, bweights, velc, vweights, scat, selfscat, coeff,
        W0t, W1t, W2t, S0t, S1t, tb0, tb1, tb2, sb0, sb1, outw, out);
}

// Round 6
// 291.660 us; speedup vs baseline: 3.6223x; 1.0328x over previous
//
#include <hip/hip_runtime.h>
#include <hip/hip_bf16.h>

#define BB 4
#define NN 32
#define MM 64
#define KK 16
#define KK1 17
#define PP 128
#define CC 2

typedef unsigned short ushort_t;
typedef unsigned int uint32;
typedef __attribute__((ext_vector_type(8))) short bhalf8;
typedef __attribute__((ext_vector_type(4))) float floatx4;

__device__ __forceinline__ float fast_tanh(float x) {
    float e = __expf(2.0f * x);
    return 1.0f - 2.0f / (e + 1.0f);
}
__device__ __forceinline__ ushort_t f2b(float f) {
    uint32 u = __float_as_uint(f);
    return (ushort_t)((u + 0x8000u) >> 16);
}
__device__ __forceinline__ float b2f(ushort_t h) {
    return __uint_as_float(((uint32)h) << 16);
}

// ---------------------------------------------------------------------------
// Prep: weights -> bf16 B-operand layouts + w_ws[b*64+m][256] = xp,vp part of
// L0 pre-activation with tb0 folded in (bf16).
// ---------------------------------------------------------------------------
__global__ void prep_kernel(const float* __restrict__ tw0, const float* __restrict__ tw1,
                            const float* __restrict__ tw2, const float* __restrict__ sw0,
                            const float* __restrict__ sw1, const float* __restrict__ aw0,
                            const float* __restrict__ aw1, const float* __restrict__ tb0,
                            const float* __restrict__ bcoord,
                            ushort_t* __restrict__ W1t, ushort_t* __restrict__ W2t,
                            ushort_t* __restrict__ S0t, ushort_t* __restrict__ S1t,
                            ushort_t* __restrict__ W0a, ushort_t* __restrict__ W1a,
                            ushort_t* __restrict__ w_ws) {
    int i = blockIdx.x * 256 + threadIdx.x;
    if (i < 65536) {
        int nn = i >> 8, k = i & 255;
        W1t[i] = f2b(tw1[k * 256 + nn]);
    } else if (i < 98304) {
        int j = i - 65536; int nn = j >> 8, k = j & 255;
        W2t[j] = f2b(tw2[k * 128 + nn]);
    } else if (i < 114688) {
        S0t[i - 98304] = f2b(sw0[i - 98304]);
    } else if (i < 131072) {
        S1t[i - 114688] = f2b(sw1[i - 114688]);
    } else if (i < 133120) {
        int j = i - 131072; int nn = j >> 5, k = j & 31;
        W0a[j] = (k < 6) ? f2b(aw0[k * 64 + nn]) : (ushort_t)0;
    } else if (i < 137216) {
        int j = i - 133120; int nn = j >> 6, k = j & 63;
        W1a[j] = f2b(aw1[k * 64 + nn]);
    } else if (i < 202752) {
        int j = i - 137216;
        int m = j >> 8, c = j & 255;   // m = b*64 + mm
        float v = bcoord[m * 4 + 0] * tw0[4 * 256 + c]
                + bcoord[m * 4 + 1] * tw0[5 * 256 + c]
                + bcoord[m * 4 + 2] * tw0[6 * 256 + c]
                + bcoord[m * 4 + 3] * tw0[7 * 256 + c]
                + tb0[c];
        w_ws[j] = f2b(v);
    }
}

// ---------------------------------------------------------------------------
// Kernel A (MFMA attn): block per (b,n,k); 128 thr. Also emits
// u_ws[bn*17+k][256] = x,vall,coeff part of the transport L0 pre-activation.
// ---------------------------------------------------------------------------
#define AH0S 72

__global__ __launch_bounds__(128) void attn_kernel(
    const float* __restrict__ phase, const float* __restrict__ posc,
    const float* __restrict__ sigma, const float* __restrict__ velc,
    const ushort_t* __restrict__ W0a, const ushort_t* __restrict__ W1a,
    const float* __restrict__ ab0, const float* __restrict__ ab1,
    const float* __restrict__ aw2, const float* __restrict__ ab2,
    const float* __restrict__ tw0, ushort_t* __restrict__ u_ws)
{
    __shared__ __align__(16) ushort_t sA0[128 * 32];
    __shared__ __align__(16) ushort_t sH0[128 * AH0S];
    __shared__ float sPL[128];
    __shared__ float sLG[128];
    __shared__ float s_red[8];

    const int tid = threadIdx.x;
    const int wave = tid >> 6;
    const int lane = tid & 63;
    const int lrow = lane & 15;
    const int lkg  = lane >> 4;

    const int blk = blockIdx.x;
    const int b = blk / (NN * KK1);
    const int rem = blk % (NN * KK1);
    const int n = rem / KK1;
    const int k = rem % KK1;

    float x0, x1, va0, va1;
    {
        const int p = tid;
        x0 = phase[(b * NN + n) * 4 + 0];
        x1 = phase[(b * NN + n) * 4 + 1];
        if (k == 0) { va0 = phase[(b * NN + n) * 4 + 2]; va1 = phase[(b * NN + n) * 4 + 3]; }
        else { va0 = velc[(b * KK + (k - 1)) * 2 + 0]; va1 = velc[(b * KK + (k - 1)) * 2 + 1]; }
        const float inv = rsqrtf(va0 * va0 + va1 * va1 + 1e-16f);
        const float ag0 = va0 * inv, ag1 = va1 * inv;
        const float px = posc[(b * PP + p) * 2 + 0];
        const float py = posc[(b * PP + p) * 2 + 1];
        const float r0 = x0 - px, r1 = x1 - py;
        const float rd = sqrtf(r0 * r0 + r1 * r1 + 1e-16f);
        const float pl = r0 * ag0 + r1 * ag1;
        const float al = pl / (rd + 1e-8f);
        sPL[p] = pl;
        bhalf8 f0;
        f0[0] = (short)f2b(x0); f0[1] = (short)f2b(x1);
        f0[2] = (short)f2b(va0); f0[3] = (short)f2b(va1);
        f0[4] = (short)f2b(al); f0[5] = (short)f2b(pl);
        f0[6] = 0; f0[7] = 0;
        bhalf8 z = {0, 0, 0, 0, 0, 0, 0, 0};
        *(bhalf8*)&sA0[p * 32 + 0] = f0;
        *(bhalf8*)&sA0[p * 32 + 8] = z;   // zero padding cols (NaN-safe for 0*A)
        *(bhalf8*)&sA0[p * 32 + 16] = z;
        *(bhalf8*)&sA0[p * 32 + 24] = z;
    }
    __syncthreads();

    // ---- L1: h0 = tanh(A0 @ W0a + ab0) ----
    {
        float b0v[4];
        #pragma unroll
        for (int j = 0; j < 4; ++j) b0v[j] = ab0[j * 16 + lrow];
        bhalf8 a[4];
        #pragma unroll
        for (int mtl = 0; mtl < 4; ++mtl)
            a[mtl] = *(const bhalf8*)&sA0[(wave * 64 + mtl * 16 + lrow) * 32 + lkg * 8];
        #pragma unroll
        for (int j = 0; j < 4; ++j) {
            bhalf8 bf = *(const bhalf8*)(W0a + (j * 16 + lrow) * 32 + lkg * 8);
            #pragma unroll
            for (int mtl = 0; mtl < 4; ++mtl) {
                floatx4 c = {0.f, 0.f, 0.f, 0.f};
                c = __builtin_amdgcn_mfma_f32_16x16x32_bf16(a[mtl], bf, c, 0, 0, 0);
                #pragma unroll
                for (int q = 0; q < 4; ++q) {
                    int row = wave * 64 + mtl * 16 + lkg * 4 + q;
                    sH0[row * AH0S + j * 16 + lrow] = f2b(fast_tanh(c[q] + b0v[j]));
                }
            }
        }
    }
    __syncthreads();

    // ---- L2 + logit ----
    {
        float b1v[4], w2v[4];
        #pragma unroll
        for (int j = 0; j < 4; ++j) { b1v[j] = ab1[j * 16 + lrow]; w2v[j] = aw2[j * 16 + lrow]; }
        bhalf8 a0[4], a1[4];
        #pragma unroll
        for (int mtl = 0; mtl < 4; ++mtl) {
            int base = (wave * 64 + mtl * 16 + lrow) * AH0S;
            a0[mtl] = *(const bhalf8*)&sH0[base + lkg * 8];
            a1[mtl] = *(const bhalf8*)&sH0[base + 32 + lkg * 8];
        }
        float s[4][4];
        #pragma unroll
        for (int mtl = 0; mtl < 4; ++mtl)
            #pragma unroll
            for (int q = 0; q < 4; ++q) s[mtl][q] = 0.0f;
        #pragma unroll
        for (int j = 0; j < 4; ++j) {
            bhalf8 bf0 = *(const bhalf8*)(W1a + (j * 16 + lrow) * 64 + lkg * 8);
            bhalf8 bf1 = *(const bhalf8*)(W1a + (j * 16 + lrow) * 64 + 32 + lkg * 8);
            #pragma unroll
            for (int mtl = 0; mtl < 4; ++mtl) {
                floatx4 c = {0.f, 0.f, 0.f, 0.f};
                c = __builtin_amdgcn_mfma_f32_16x16x32_bf16(a0[mtl], bf0, c, 0, 0, 0);
                c = __builtin_amdgcn_mfma_f32_16x16x32_bf16(a1[mtl], bf1, c, 0, 0, 0);
                #pragma unroll
                for (int q = 0; q < 4; ++q)
                    s[mtl][q] += fast_tanh(c[q] + b1v[j]) * w2v[j];
            }
        }
        #pragma unroll
        for (int mask = 1; mask <= 8; mask <<= 1)
            #pragma unroll
            for (int mtl = 0; mtl < 4; ++mtl)
                #pragma unroll
                for (int q = 0; q < 4; ++q)
                    s[mtl][q] += __shfl_xor(s[mtl][q], mask, 64);
        if (lrow == 0) {
            #pragma unroll
            for (int mtl = 0; mtl < 4; ++mtl)
                #pragma unroll
                for (int q = 0; q < 4; ++q)
                    sLG[wave * 64 + mtl * 16 + lkg * 4 + q] = s[mtl][q];
        }
    }
    __syncthreads();

    // ---- softmax + coeff -> u emit ----
    {
        const int p = tid;
        const float ml = (sPL[p] > 0.0f) ? (sLG[p] + ab2[0]) : -1e30f;
        const int wid = wave;
        float mv = ml;
        for (int o = 32; o > 0; o >>= 1) mv = fmaxf(mv, __shfl_xor(mv, o, 64));
        if (lane == 0) s_red[wid] = mv;
        __syncthreads();
        mv = fmaxf(s_red[0], s_red[1]);

        const float ew = __expf(ml - mv);
        float sv = ew;
        for (int o = 32; o > 0; o >>= 1) sv += __shfl_xor(sv, o, 64);
        if (lane == 0) s_red[2 + wid] = sv;
        __syncthreads();
        sv = s_red[2] + s_red[3];
        const float attn = ew / sv;

        float s0 = attn * sigma[(b * PP + p) * 2 + 0];
        float s1 = attn * sigma[(b * PP + p) * 2 + 1];
        for (int o = 32; o > 0; o >>= 1) { s0 += __shfl_xor(s0, o, 64); s1 += __shfl_xor(s1, o, 64); }
        if (lane == 0) { s_red[4 + wid] = s0; s_red[6 + wid] = s1; }
        __syncthreads();

        const float cc0 = __expf(-(s_red[4] + s_red[5]));
        const float cc1 = __expf(-(s_red[6] + s_red[7]));
        // u[c] = x.tw0[0:2] + vall.tw0[2:4] + coeff.tw0[8:10]
        const int ubase = ((b * NN + n) * KK1 + k) * 256;
        for (int cc = tid; cc < 256; cc += 128) {
            float uv = x0 * tw0[cc] + x1 * tw0[256 + cc]
                     + va0 * tw0[512 + cc] + va1 * tw0[768 + cc]
                     + cc0 * tw0[2048 + cc] + cc1 * tw0[2304 + cc];
            u_ws[ubase + cc] = f2b(uv);
        }
    }
}

// ---------------------------------------------------------------------------
// Kernel B: MFMA transport, L0 replaced by h0 = tanh(u+w) fill (K-chunked).
// LDS 40536 B -> 4 blocks/CU. 8 barriers. GTS/V2T stride 40 (2-way banks).
// Regions (u16 idx):
//   X [0,6152):  H0A(34x136) -> GTS(128x40+8) + GV/NEWV(bf16) + A2S
//   Y [6152,15128): H1A(34x264) -> AS2(34x136) -> A3(16x136, aliases AS2)
//   Z [15128,20248): AS(17x32) -> V2T(128x40)
//   BBW/RED [20256 B.. ): floats at u 20256..20268
// ---------------------------------------------------------------------------
#define H0S  136
#define H1S  264
#define GTSs 40
#define AS2S 136
#define V2S  40

#define U_H0A  0
#define U_GTS  0        // alloc 5128 (row127 tail readable)
#define U_GV   5128     // bf16 [5128,5384)
#define U_NEWV 5384     // bf16 [5384,5640)
#define U_A2S  5640     // [5640,6152)
#define U_H1A  6152
#define U_AS2  6152
#define U_A3   6152     // aliases AS2 (disjoint lifetime)
#define U_AS   15128    // [15128,15672)
#define U_V2T  15128    // [15128,20248) aliases AS (disjoint lifetime)
#define F_BBW  10128    // u 20256..20260
#define F_RED  10130    // u 20260..20268

__global__ __launch_bounds__(256, 4) void transport_kernel(
    const float* __restrict__ boundary, const float* __restrict__ bweights,
    const float* __restrict__ vweights, const float* __restrict__ scat,
    const float* __restrict__ selfscat,
    const ushort_t* __restrict__ W1t, const ushort_t* __restrict__ W2t,
    const ushort_t* __restrict__ S0t, const ushort_t* __restrict__ S1t,
    const float* __restrict__ tb1, const float* __restrict__ tb2,
    const float* __restrict__ sb0, const float* __restrict__ sb1,
    const float* __restrict__ outw,
    const ushort_t* __restrict__ u_ws, const ushort_t* __restrict__ w_ws,
    float* __restrict__ out)
{
    __shared__ __align__(16) ushort_t smem[20268];
    float* smf = (float*)smem;

    const int tid = threadIdx.x;
    const int wave = tid >> 6;
    const int lane = tid & 63;
    const int lrow = lane & 15;
    const int lkg  = lane >> 4;

    const int blk = blockIdx.x;
    const int b  = blk >> 10;
    const int n  = (blk >> 5) & 31;
    const int mg = blk & 31;
    const int m0 = mg * 2;
    const int bn = b * NN + n;

    if (tid < 2)
        smf[F_BBW + tid] = boundary[b * MM + m0 + tid] * bweights[b * MM + m0 + tid];

    // ---- AS build (Z) ----
    for (int idx = tid; idx < 17 * 32; idx += 256) {
        int i = idx >> 5, c = idx & 31;
        float val = 0.0f;
        if (c < 16) {
            float vw = vweights[b * KK + c];
            val = (i < 16) ? (1.0f - selfscat[(b * KK + i) * KK + c]) * vw
                           : (1.0f - scat[bn * KK + c]) * vw;
        }
        smem[U_AS + idx] = f2b(val);
    }

    // ---- L1 with K-chunked h0 fill (no L0 MFMA: h0 = tanh(u+w)) ----
    floatx4 c1[4][3];
    #pragma unroll
    for (int j = 0; j < 4; ++j)
        #pragma unroll
        for (int mt = 0; mt < 3; ++mt) c1[j][mt] = (floatx4){0.f, 0.f, 0.f, 0.f};

    for (int chunk = 0; chunk < 2; ++chunk) {
        if (chunk) __syncthreads();   // waves done reading H0A chunk0
        for (int idx = tid; idx < 34 * 16; idx += 256) {
            int row = idx >> 4, oct = idx & 15;
            int ml = (row >= 17);
            int k = row - ml * 17;
            bhalf8 uu = *(const bhalf8*)(u_ws + (bn * KK1 + k) * 256 + chunk * 128 + oct * 8);
            bhalf8 ww = *(const bhalf8*)(w_ws + (b * MM + m0 + ml) * 256 + chunk * 128 + oct * 8);
            bhalf8 hh;
            #pragma unroll
            for (int jj = 0; jj < 8; ++jj)
                hh[jj] = (short)f2b(fast_tanh(b2f((ushort_t)uu[jj]) + b2f((ushort_t)ww[jj])));
            *(bhalf8*)&smem[U_H0A + row * H0S + oct * 8] = hh;
        }
        __syncthreads();
        #pragma unroll
        for (int ksl = 0; ksl < 4; ++ksl) {
            bhalf8 a[3];
            #pragma unroll
            for (int mt = 0; mt < 3; ++mt)
                a[mt] = *(const bhalf8*)&smem[U_H0A + (mt * 16 + lrow) * H0S + ksl * 32 + lkg * 8];
            #pragma unroll
            for (int j = 0; j < 4; ++j) {
                bhalf8 bf = *(const bhalf8*)(W1t + ((4 * wave + j) * 16 + lrow) * 256
                                             + chunk * 128 + ksl * 32 + lkg * 8);
                #pragma unroll
                for (int mt = 0; mt < 3; ++mt)
                    c1[j][mt] = __builtin_amdgcn_mfma_f32_16x16x32_bf16(a[mt], bf, c1[j][mt], 0, 0, 0);
            }
        }
    }
    // L1 epilogue -> H1A (Y)
    {
        #pragma unroll
        for (int j = 0; j < 4; ++j) {
            float bb = tb1[(4 * wave + j) * 16 + lrow];
            #pragma unroll
            for (int mt = 0; mt < 3; ++mt)
                #pragma unroll
                for (int q = 0; q < 4; ++q) {
                    int row = mt * 16 + lkg * 4 + q;
                    if (row < 34)
                        smem[U_H1A + row * H1S + (4 * wave + j) * 16 + lrow] =
                            f2b(fast_tanh(c1[j][mt][q] + bb));
                }
        }
    }
    __syncthreads();

    // ---- L2: g = exp(tanh(h1A@W2t+tb2)) -> GTS/GV (X). Zero GTS pad cells. ----
    for (int idx = tid; idx < 1032; idx += 256) {
        int pos = (idx < 1024) ? ((idx >> 3) * GTSs + 32 + (idx & 7)) : (5120 + idx - 1024);
        smem[U_GTS + pos] = 0;
    }
    {
        floatx4 c2[2][3];
        #pragma unroll
        for (int j = 0; j < 2; ++j)
            #pragma unroll
            for (int mt = 0; mt < 3; ++mt) c2[j][mt] = (floatx4){0.f, 0.f, 0.f, 0.f};
        #pragma unroll
        for (int ks = 0; ks < 8; ++ks) {
            bhalf8 a[3];
            #pragma unroll
            for (int mt = 0; mt < 3; ++mt)
                a[mt] = *(const bhalf8*)&smem[U_H1A + (mt * 16 + lrow) * H1S + ks * 32 + lkg * 8];
            #pragma unroll
            for (int j = 0; j < 2; ++j) {
                bhalf8 bf = *(const bhalf8*)(W2t + ((2 * wave + j) * 16 + lrow) * 256 + ks * 32 + lkg * 8);
                #pragma unroll
                for (int mt = 0; mt < 3; ++mt)
                    c2[j][mt] = __builtin_amdgcn_mfma_f32_16x16x32_bf16(a[mt], bf, c2[j][mt], 0, 0, 0);
            }
        }
        #pragma unroll
        for (int j = 0; j < 2; ++j) {
            float bb = tb2[(2 * wave + j) * 16 + lrow];
            #pragma unroll
            for (int mt = 0; mt < 3; ++mt)
                #pragma unroll
                for (int q = 0; q < 4; ++q) {
                    int row = mt * 16 + lkg * 4 + q;
                    if (row < 34) {
                        int ml = (row >= 17);
                        int k = row - ml * 17;
                        int col = (2 * wave + j) * 16 + lrow;
                        float g = __expf(fast_tanh(c2[j][mt][q] + bb));
                        if (k == 0) smem[U_GV + ml * 128 + col] = f2b(g);
                        else        smem[U_GTS + col * GTSs + ml * 16 + (k - 1)] = f2b(g);
                    }
                }
        }
    }
    __syncthreads();

    // ---- resvs (AS @ GTS -> AS2) + A2S build ----
    for (int idx = tid; idx < 512; idx += 256) {
        int r = idx >> 5, c = idx & 31;
        smem[U_A2S + idx] = ((c >> 4) == r) ? smem[U_AS + 16 * 32 + (c & 15)] : (ushort_t)0;
    }
    {
        bhalf8 a0 = *(const bhalf8*)&smem[U_AS + lrow * 32 + lkg * 8];
        bhalf8 a1 = *(const bhalf8*)&smem[U_AS + (16 + lrow) * 32 + lkg * 8];
        for (int m = 0; m < 2; ++m) {
            #pragma unroll
            for (int j = 0; j < 2; ++j) {
                int nt = 2 * wave + j;
                bhalf8 bf = *(const bhalf8*)&smem[U_GTS + (nt * 16 + lrow) * GTSs + m * 16 + lkg * 8];
                #pragma unroll
                for (int mt = 0; mt < 2; ++mt) {
                    floatx4 c = {0.f, 0.f, 0.f, 0.f};
                    c = __builtin_amdgcn_mfma_f32_16x16x32_bf16(mt ? a1 : a0, bf, c, 0, 0, 0);
                    #pragma unroll
                    for (int q = 0; q < 4; ++q) {
                        int ic = mt * 16 + lkg * 4 + q;
                        if (ic < 17) {
                            int r2 = (ic == 16) ? m * 17 : m * 17 + 1 + ic;
                            smem[U_AS2 + r2 * AS2S + nt * 16 + lrow] = f2b(c[q]);
                        }
                    }
                }
            }
        }
    }
    __syncthreads();

    // ---- sw0: tanh(AS2@S0t+sb0) -> NEWV(bf16, X) / V2T(Z) ----
    {
        floatx4 c3[2][3];
        #pragma unroll
        for (int j = 0; j < 2; ++j)
            #pragma unroll
            for (int mt = 0; mt < 3; ++mt) c3[j][mt] = (floatx4){0.f, 0.f, 0.f, 0.f};
        #pragma unroll
        for (int ks = 0; ks < 4; ++ks) {
            bhalf8 a[3];
            #pragma unroll
            for (int mt = 0; mt < 3; ++mt)
                a[mt] = *(const bhalf8*)&smem[U_AS2 + (mt * 16 + lrow) * AS2S + ks * 32 + lkg * 8];
            #pragma unroll
            for (int j = 0; j < 2; ++j) {
                bhalf8 bf = *(const bhalf8*)(S0t + ((2 * wave + j) * 16 + lrow) * 128 + ks * 32 + lkg * 8);
                #pragma unroll
                for (int mt = 0; mt < 3; ++mt)
                    c3[j][mt] = __builtin_amdgcn_mfma_f32_16x16x32_bf16(a[mt], bf, c3[j][mt], 0, 0, 0);
            }
        }
        #pragma unroll
        for (int j = 0; j < 2; ++j) {
            float bb = sb0[(2 * wave + j) * 16 + lrow];
            #pragma unroll
            for (int mt = 0; mt < 3; ++mt)
                #pragma unroll
                for (int q = 0; q < 4; ++q) {
                    int r2 = mt * 16 + lkg * 4 + q;
                    if (r2 < 34) {
                        int m = (r2 >= 17);
                        int i2 = r2 - m * 17;
                        int col = (2 * wave + j) * 16 + lrow;
                        float val = fast_tanh(c3[j][mt][q] + bb);
                        if (i2 == 0) {
                            smem[U_NEWV + m * 128 + col] =
                                f2b(b2f(smem[U_GV + m * 128 + col]) + val);
                        } else {
                            int j2 = i2 - 1;
                            smem[U_V2T + col * V2S + m * 16 + j2] =
                                f2b(b2f(smem[U_GTS + col * GTSs + m * 16 + j2]) + val);
                        }
                    }
                }
        }
    }
    __syncthreads();

    // ---- resv2: A2S @ V2T -> A3 (Y, aliases dead AS2) ----
    {
        bhalf8 a = *(const bhalf8*)&smem[U_A2S + lrow * 32 + lkg * 8];
        #pragma unroll
        for (int j = 0; j < 2; ++j) {
            int nt = 2 * wave + j;
            bhalf8 bf = *(const bhalf8*)&smem[U_V2T + (nt * 16 + lrow) * V2S + lkg * 8];
            floatx4 c = {0.f, 0.f, 0.f, 0.f};
            c = __builtin_amdgcn_mfma_f32_16x16x32_bf16(a, bf, c, 0, 0, 0);
            #pragma unroll
            for (int q = 0; q < 4; ++q) {
                int r = lkg * 4 + q;
                smem[U_A3 + r * AS2S + nt * 16 + lrow] = f2b(c[q]);
            }
        }
    }
    __syncthreads();

    // ---- green + output ----
    float acc = 0.0f;
    {
        bhalf8 a[4];
        #pragma unroll
        for (int ks = 0; ks < 4; ++ks)
            a[ks] = *(const bhalf8*)&smem[U_A3 + lrow * AS2S + ks * 32 + lkg * 8];
        #pragma unroll
        for (int j = 0; j < 2; ++j) {
            int nt = 2 * wave + j;
            float s1v = sb1[nt * 16 + lrow];
            float owv = outw[nt * 16 + lrow];
            floatx4 c = {0.f, 0.f, 0.f, 0.f};
            #pragma unroll
            for (int ks = 0; ks < 4; ++ks) {
                bhalf8 bf = *(const bhalf8*)(S1t + (nt * 16 + lrow) * 128 + ks * 32 + lkg * 8);
                c = __builtin_amdgcn_mfma_f32_16x16x32_bf16(a[ks], bf, c, 0, 0, 0);
            }
            #pragma unroll
            for (int q = 0; q < 4; ++q) {
                int r = lkg * 4 + q;
                if (r < 2) {
                    int col = nt * 16 + lrow;
                    float green = b2f(smem[U_NEWV + r * 128 + col]) + fast_tanh(c[q] + s1v);
                    acc += green * owv * smf[F_BBW + r];
                }
            }
        }
    }
    for (int o = 32; o > 0; o >>= 1) acc += __shfl_xor(acc, o, 64);
    if (lane == 0) smf[F_RED + wave] = acc;
    __syncthreads();
    if (tid == 0) {
        float tot = smf[F_RED + 0] + smf[F_RED + 1] + smf[F_RED + 2] + smf[F_RED + 3];
        atomicAdd(&out[bn], tot);
    }
}

extern "C" void kernel_launch(void* const* d_in, const int* in_sizes, int n_in,
                              void* d_out, int out_size, void* d_ws, size_t ws_size,
                              hipStream_t stream) {
    const float* phase    = (const float*)d_in[0];
    const float* bcoord   = (const float*)d_in[1];
    const float* boundary = (const float*)d_in[2];
    const float* bweights = (const float*)d_in[3];
    const float* posc     = (const float*)d_in[4];
    const float* sigma    = (const float*)d_in[5];
    const float* velc     = (const float*)d_in[6];
    const float* vweights = (const float*)d_in[7];
    const float* scat     = (const float*)d_in[8];
    const float* selfscat = (const float*)d_in[9];
    const float* aw0 = (const float*)d_in[10];
    const float* ab0 = (const float*)d_in[11];
    const float* aw1 = (const float*)d_in[12];
    const float* ab1 = (const float*)d_in[13];
    const float* aw2 = (const float*)d_in[14];
    const float* ab2 = (const float*)d_in[15];
    const float* tw0 = (const float*)d_in[16];
    const float* tb0 = (const float*)d_in[17];
    const float* tw1 = (const float*)d_in[18];
    const float* tb1 = (const float*)d_in[19];
    const float* tw2 = (const float*)d_in[20];
    const float* tb2 = (const float*)d_in[21];
    const float* sw0 = (const float*)d_in[22];
    const float* sb0 = (const float*)d_in[23];
    const float* sw1 = (const float*)d_in[24];
    const float* sb1 = (const float*)d_in[25];
    const float* outw = (const float*)d_in[26];

    float* out = (float*)d_out;
    char* ws = (char*)d_ws;
    ushort_t* W1t  = (ushort_t*)(ws + 0);         // 131072 B
    ushort_t* W2t  = (ushort_t*)(ws + 131072);    // 65536 B
    ushort_t* S0t  = (ushort_t*)(ws + 196608);    // 32768 B
    ushort_t* S1t  = (ushort_t*)(ws + 229376);    // 32768 B
    ushort_t* W0a  = (ushort_t*)(ws + 262144);    // 4096 B
    ushort_t* W1a  = (ushort_t*)(ws + 266240);    // 8192 B
    ushort_t* u_ws = (ushort_t*)(ws + 274432);    // 2176*256*2 = 1114112 B
    ushort_t* w_ws = (ushort_t*)(ws + 1388544);   // 256*256*2 = 131072 B -> 1519616 total

    hipMemsetAsync(d_out, 0, (size_t)out_size * sizeof(float), stream);

    prep_kernel<<<792, 256, 0, stream>>>(tw0, tw1, tw2, sw0, sw1, aw0, aw1, tb0, bcoord,
                                         W1t, W2t, S0t, S1t, W0a, W1a, w_ws);

    attn_kernel<<<BB * NN * KK1, 128, 0, stream>>>(
        phase, posc, sigma, velc, W0a, W1a, ab0, ab1, aw2, ab2, tw0, u_ws);

    transport_kernel<<<BB * NN * 32, 256, 0, stream>>>(
        boundary, bweights, vweights, scat, selfscat,
        W1t, W2t, S0t, S1t, tb1, tb2, sb0, sb1, outw, u_ws, w_ws, out);
}